// Round 2
// baseline (8066.198 us; speedup 1.0000x reference)
//
#include <hip/hip_runtime.h>

namespace {

constexpr int NN  = 200000;   // nodes
constexpr int NE  = 3200000;  // edges
constexpr int NR  = 20;       // relations
constexpr int FIN = 16;
constexpr int H1D = 16;
constexpr int H2D = 32;
constexpr int NC  = 2;
constexpr int NG  = 64;

constexpr int TPB = 256;

// ---------------- kernel 1: per-(relation,dst) in-degree counts ----------------
__global__ __launch_bounds__(TPB) void count_kernel(
    const int* __restrict__ etype, const int* __restrict__ dst,
    int* __restrict__ counts) {
  int e = blockIdx.x * TPB + threadIdx.x;
  if (e < NE) atomicAdd(&counts[etype[e] * NN + dst[e]], 1);
}

// ---------------- kernel 2: layer-1 edge messages ----------------
// agg1[d] += (x[s] @ W1[r]) / counts[r,d]
__global__ __launch_bounds__(TPB) void edge1_kernel(
    const float* __restrict__ x, const int* __restrict__ src,
    const int* __restrict__ dst, const int* __restrict__ etype,
    const int* __restrict__ counts, const float* __restrict__ W1,
    float* __restrict__ agg1) {
  // 20 relation matrices (16x16) in LDS, per-relation stride 257 (257 % 32 == 1
  // -> lanes with distinct r hit distinct banks)
  __shared__ float Ws[NR * 257];
  for (int i = threadIdx.x; i < NR * 256; i += TPB)
    Ws[(i >> 8) * 257 + (i & 255)] = W1[i];
  __syncthreads();

  int e = blockIdx.x * TPB + threadIdx.x;
  if (e >= NE) return;
  int s = src[e], d = dst[e], r = etype[e];
  float norm = 1.0f / (float)counts[r * NN + d];

  float xv[FIN];
  const float4* xs = (const float4*)(x + s * FIN);
  ((float4*)xv)[0] = xs[0];
  ((float4*)xv)[1] = xs[1];
  ((float4*)xv)[2] = xs[2];
  ((float4*)xv)[3] = xs[3];

  const float* W = &Ws[r * 257];
  float* aout = agg1 + d * H1D;
#pragma unroll
  for (int j = 0; j < H1D; ++j) {
    float acc = 0.f;
#pragma unroll
    for (int i = 0; i < FIN; ++i) acc = fmaf(xv[i], W[i * H1D + j], acc);
    atomicAdd(aout + j, acc * norm);
  }
}

// ---------------- kernel 3: layer-1 node combine ----------------
// h1[n] = relu(agg1[n] + x[n] @ root1 + b1)
__global__ __launch_bounds__(TPB) void node1_kernel(
    const float* __restrict__ x, const float* __restrict__ agg1,
    const float* __restrict__ root1, const float* __restrict__ b1,
    float* __restrict__ h1) {
  __shared__ float Rs[FIN * H1D];
  __shared__ float Bs[H1D];
  for (int i = threadIdx.x; i < FIN * H1D; i += TPB) Rs[i] = root1[i];
  if (threadIdx.x < H1D) Bs[threadIdx.x] = b1[threadIdx.x];
  __syncthreads();

  int n = blockIdx.x * TPB + threadIdx.x;
  if (n >= NN) return;

  float xv[FIN], av[H1D];
  const float4* xs = (const float4*)(x + n * FIN);
  const float4* as = (const float4*)(agg1 + n * H1D);
#pragma unroll
  for (int k = 0; k < 4; ++k) { ((float4*)xv)[k] = xs[k]; ((float4*)av)[k] = as[k]; }

  float out[H1D];
#pragma unroll
  for (int j = 0; j < H1D; ++j) {
    float acc = Bs[j] + av[j];
#pragma unroll
    for (int i = 0; i < FIN; ++i) acc = fmaf(xv[i], Rs[i * H1D + j], acc);
    out[j] = fmaxf(acc, 0.f);
  }
  float4* hs = (float4*)(h1 + n * H1D);
#pragma unroll
  for (int k = 0; k < 4; ++k) hs[k] = ((float4*)out)[k];
}

// ---------------- kernel 4: layer-2 edge messages ----------------
__global__ __launch_bounds__(TPB) void edge2_kernel(
    const float* __restrict__ h1, const int* __restrict__ src,
    const int* __restrict__ dst, const int* __restrict__ etype,
    const int* __restrict__ counts, const float* __restrict__ W2,
    float* __restrict__ agg2) {
  // 20 relation matrices (16x32), per-relation stride 513 (513 % 32 == 1)
  __shared__ float Ws[NR * 513];
  for (int i = threadIdx.x; i < NR * 512; i += TPB)
    Ws[(i >> 9) * 513 + (i & 511)] = W2[i];
  __syncthreads();

  int e = blockIdx.x * TPB + threadIdx.x;
  if (e >= NE) return;
  int s = src[e], d = dst[e], r = etype[e];
  float norm = 1.0f / (float)counts[r * NN + d];

  float hv[H1D];
  const float4* hs = (const float4*)(h1 + s * H1D);
#pragma unroll
  for (int k = 0; k < 4; ++k) ((float4*)hv)[k] = hs[k];

  const float* W = &Ws[r * 513];
  float* aout = agg2 + d * H2D;
#pragma unroll
  for (int j = 0; j < H2D; ++j) {
    float acc = 0.f;
#pragma unroll
    for (int i = 0; i < H1D; ++i) acc = fmaf(hv[i], W[i * H2D + j], acc);
    atomicAdd(aout + j, acc * norm);
  }
}

// ---------------- kernel 5: layer-2 node combine + graph pool partials ----------------
__global__ __launch_bounds__(TPB) void node2_pool_kernel(
    const float* __restrict__ h1, const float* __restrict__ agg2,
    const float* __restrict__ root2, const float* __restrict__ b2,
    const int* __restrict__ batch,
    float* __restrict__ gsum, float* __restrict__ gcnt) {
  __shared__ float Rs[H1D * H2D];
  __shared__ float Bs[H2D];
  __shared__ float Gs[NG * H2D];  // 8 KB per-block graph partial sums
  __shared__ float Gc[NG];
  for (int i = threadIdx.x; i < H1D * H2D; i += TPB) Rs[i] = root2[i];
  for (int i = threadIdx.x; i < NG * H2D; i += TPB) Gs[i] = 0.f;
  if (threadIdx.x < NG) Gc[threadIdx.x] = 0.f;
  if (threadIdx.x < H2D) Bs[threadIdx.x] = b2[threadIdx.x];
  __syncthreads();

  int n = blockIdx.x * TPB + threadIdx.x;
  if (n < NN) {
    int g = batch[n];
    float hv[H1D];
    const float4* hsrc = (const float4*)(h1 + n * H1D);
#pragma unroll
    for (int k = 0; k < 4; ++k) ((float4*)hv)[k] = hsrc[k];
    float av[H2D];
    const float4* as = (const float4*)(agg2 + n * H2D);
#pragma unroll
    for (int k = 0; k < 8; ++k) ((float4*)av)[k] = as[k];

#pragma unroll
    for (int j = 0; j < H2D; ++j) {
      float acc = Bs[j] + av[j];
#pragma unroll
      for (int i = 0; i < H1D; ++i) acc = fmaf(hv[i], Rs[i * H2D + j], acc);
      acc = fmaxf(acc, 0.f);
      atomicAdd(&Gs[g * H2D + j], acc);
    }
    atomicAdd(&Gc[g], 1.0f);
  }
  __syncthreads();

  // flush nonzero partials (skipping exact zeros is a numerical no-op)
  for (int i = threadIdx.x; i < NG * H2D; i += TPB) {
    float v = Gs[i];
    if (v != 0.f) atomicAdd(&gsum[i], v);
  }
  for (int i = threadIdx.x; i < NG; i += TPB) {
    float v = Gc[i];
    if (v != 0.f) atomicAdd(&gcnt[i], v);
  }
}

// ---------------- kernel 6: final head ----------------
__global__ __launch_bounds__(128) void final_kernel(
    const float* __restrict__ gsum, const float* __restrict__ gcnt,
    const float* __restrict__ fcW, const float* __restrict__ fcb,
    float* __restrict__ out) {
  int t = threadIdx.x;
  if (t >= NG * NC) return;
  int g = t >> 1, c = t & 1;
  float cnt = fmaxf(gcnt[g], 1.0f);
  float acc = fcb[c];
#pragma unroll
  for (int j = 0; j < H2D; ++j)
    acc = fmaf(gsum[g * H2D + j] / cnt, fcW[j * NC + c], acc);
  out[t] = acc;
}

}  // namespace

extern "C" void kernel_launch(void* const* d_in, const int* in_sizes, int n_in,
                              void* d_out, int out_size, void* d_ws, size_t ws_size,
                              hipStream_t stream) {
  (void)in_sizes; (void)n_in; (void)out_size; (void)ws_size;

  const float* x     = (const float*)d_in[0];
  const int*   ei    = (const int*)d_in[1];
  const int*   etype = (const int*)d_in[2];
  const int*   batch = (const int*)d_in[3];
  const float* W1    = (const float*)d_in[4];
  const float* root1 = (const float*)d_in[5];
  const float* b1    = (const float*)d_in[6];
  const float* W2    = (const float*)d_in[7];
  const float* root2 = (const float*)d_in[8];
  const float* b2    = (const float*)d_in[9];
  const float* fcW   = (const float*)d_in[10];
  const float* fcb   = (const float*)d_in[11];

  const int* src = ei;
  const int* dst = ei + NE;

  // workspace layout (offsets multiple of 256B)
  char* ws = (char*)d_ws;
  int*   counts = (int*)(ws + 0);                    // 16,000,000 B
  float* agg1   = (float*)(ws + 16000000);           // 12,800,000 B
  float* agg2   = (float*)(ws + 28800000);           // 25,600,000 B
  float* gsum   = (float*)(ws + 54400000);           //      8,192 B
  float* gcnt   = (float*)(ws + 54408192);           //        256 B
  float* h1     = (float*)(ws + 54408448);           // 12,800,000 B
  // total: 67,208,448 B

  // zero accumulators (harness poisons d_ws with 0xAA before every call)
  hipMemsetAsync(ws, 0, 54408448, stream);

  int egrid = (NE + TPB - 1) / TPB;  // 12500
  int ngrid = (NN + TPB - 1) / TPB;  // 782

  count_kernel<<<egrid, TPB, 0, stream>>>(etype, dst, counts);
  edge1_kernel<<<egrid, TPB, 0, stream>>>(x, src, dst, etype, counts, W1, agg1);
  node1_kernel<<<ngrid, TPB, 0, stream>>>(x, agg1, root1, b1, h1);
  edge2_kernel<<<egrid, TPB, 0, stream>>>(h1, src, dst, etype, counts, W2, agg2);
  node2_pool_kernel<<<ngrid, TPB, 0, stream>>>(h1, agg2, root2, b2, batch, gsum, gcnt);
  final_kernel<<<1, 128, 0, stream>>>(gsum, gcnt, fcW, fcb, (float*)d_out);
}

// Round 3
// 1140.420 us; speedup vs baseline: 7.0730x; 7.0730x over previous
//
#include <hip/hip_runtime.h>

namespace {

constexpr int NN  = 200000;   // nodes
constexpr int NE  = 3200000;  // edges
constexpr int NR  = 20;       // relations
constexpr int FIN = 16;
constexpr int H1D = 16;
constexpr int H2D = 32;
constexpr int NC  = 2;
constexpr int NG  = 64;

constexpr int TPB = 256;
constexpr int NB  = (NN + TPB - 1) / TPB;  // 782 node blocks

// ---------------- k1: per-(relation,dst) in-degree counts ----------------
__global__ __launch_bounds__(TPB) void count_kernel(
    const int* __restrict__ etype, const int* __restrict__ dst,
    int* __restrict__ counts) {
  int e = blockIdx.x * TPB + threadIdx.x;
  if (e < NE) atomicAdd(&counts[etype[e] * NN + dst[e]], 1);
}

// ---------------- k2: total in-degree per node ----------------
__global__ __launch_bounds__(TPB) void deg_kernel(
    const int* __restrict__ counts, int* __restrict__ deg) {
  int d = blockIdx.x * TPB + threadIdx.x;
  if (d >= NN) return;
  int s = 0;
#pragma unroll
  for (int r = 0; r < NR; ++r) s += counts[r * NN + d];
  deg[d] = s;
}

// ---------------- k3/k4/k5: exclusive scan of deg -> rowptr ----------------
__global__ __launch_bounds__(TPB) void scan1_kernel(
    const int* __restrict__ deg, int* __restrict__ excl, int* __restrict__ bsum) {
  __shared__ int s[TPB];
  int tid = threadIdx.x;
  int i = blockIdx.x * TPB + tid;
  int v = (i < NN) ? deg[i] : 0;
  s[tid] = v;
  __syncthreads();
  for (int off = 1; off < TPB; off <<= 1) {
    int t = 0;
    if (tid >= off) t = s[tid - off];
    __syncthreads();
    if (tid >= off) s[tid] += t;
    __syncthreads();
  }
  if (i < NN) excl[i] = s[tid] - v;           // exclusive within block
  if (tid == TPB - 1) bsum[blockIdx.x] = s[tid];
}

__global__ __launch_bounds__(1024) void scan2_kernel(
    const int* __restrict__ bsum, int* __restrict__ bofs) {
  __shared__ int s[1024];
  int tid = threadIdx.x;
  int v = (tid < NB) ? bsum[tid] : 0;
  s[tid] = v;
  __syncthreads();
  for (int off = 1; off < 1024; off <<= 1) {
    int t = 0;
    if (tid >= off) t = s[tid - off];
    __syncthreads();
    if (tid >= off) s[tid] += t;
    __syncthreads();
  }
  if (tid < NB) bofs[tid] = s[tid] - v;       // exclusive block offsets
}

__global__ __launch_bounds__(TPB) void scan3_kernel(
    int* __restrict__ rowptr, const int* __restrict__ bofs) {
  int i = blockIdx.x * TPB + threadIdx.x;
  if (i < NN) rowptr[i] += bofs[blockIdx.x];
}

// ---------------- k6: scatter edges into dst-sorted key array ----------------
// key = src | (etype << 18)   (src < 2^18, etype < 32)
__global__ __launch_bounds__(TPB) void scatter_kernel(
    const int* __restrict__ src, const int* __restrict__ dst,
    const int* __restrict__ etype, const int* __restrict__ rowptr,
    int* __restrict__ cursor, unsigned* __restrict__ keys) {
  int e = blockIdx.x * TPB + threadIdx.x;
  if (e >= NE) return;
  int d = dst[e];
  int pos = rowptr[d] + atomicAdd(&cursor[d], 1);
  keys[pos] = (unsigned)src[e] | ((unsigned)etype[e] << 18);
}

// ---------------- k7: layer-1 gather + node combine (no atomics) ----------------
// 16 lanes per node, lane j = output channel j
__global__ __launch_bounds__(TPB) void gather1_kernel(
    const float* __restrict__ x, const unsigned* __restrict__ keys,
    const int* __restrict__ rowptr, const int* __restrict__ deg,
    const int* __restrict__ counts, const float* __restrict__ W1,
    const float* __restrict__ root1, const float* __restrict__ b1,
    float* __restrict__ h1) {
  __shared__ float Ws[NR * 257];   // pad 257: per-relation bank offset
  __shared__ float Rs[FIN * H1D];
  __shared__ float Bs[H1D];
  for (int i = threadIdx.x; i < NR * 256; i += TPB)
    Ws[(i >> 8) * 257 + (i & 255)] = W1[i];
  for (int i = threadIdx.x; i < FIN * H1D; i += TPB) Rs[i] = root1[i];
  if (threadIdx.x < H1D) Bs[threadIdx.x] = b1[threadIdx.x];
  __syncthreads();

  int n = blockIdx.x * (TPB / 16) + (threadIdx.x >> 4);  // grid exact: 12500*16 == NN
  int j = threadIdx.x & 15;
  int start = rowptr[n];
  int dg = deg[n];

  float agg = 0.f;
  for (int k = 0; k < dg; ++k) {
    unsigned key = keys[start + k];          // broadcast within group
    int s = key & 0x3FFFF;
    int r = key >> 18;
    float norm = 1.f / (float)counts[r * NN + n];  // broadcast
    float xv = x[s * FIN + j];               // coalesced 64B per group
    float m = 0.f;
    const float* Wr = &Ws[r * 257 + j];
#pragma unroll
    for (int i = 0; i < FIN; ++i) m = fmaf(__shfl(xv, i, 16), Wr[i * H1D], m);
    agg = fmaf(m, norm, agg);
  }

  float xn = x[n * FIN + j];
  float acc = Bs[j] + agg;
#pragma unroll
  for (int i = 0; i < FIN; ++i) acc = fmaf(__shfl(xn, i, 16), Rs[i * H1D + j], acc);
  h1[n * FIN + j] = fmaxf(acc, 0.f);
}

// ---------------- k8: layer-2 gather + node combine + pool partials ----------------
// 16 lanes per node, lane j = channels j and j+16
__global__ __launch_bounds__(TPB) void gather2_kernel(
    const float* __restrict__ h1, const unsigned* __restrict__ keys,
    const int* __restrict__ rowptr, const int* __restrict__ deg,
    const int* __restrict__ counts, const float* __restrict__ W2,
    const float* __restrict__ root2, const float* __restrict__ b2,
    const int* __restrict__ batch,
    float* __restrict__ gsum, float* __restrict__ gcnt) {
  __shared__ float Ws[NR * 513];   // pad 513
  __shared__ float Rs[H1D * H2D];
  __shared__ float Bs[H2D];
  __shared__ float Gs[NG * H2D];
  __shared__ float Gc[NG];
  for (int i = threadIdx.x; i < NR * 512; i += TPB)
    Ws[(i >> 9) * 513 + (i & 511)] = W2[i];
  for (int i = threadIdx.x; i < H1D * H2D; i += TPB) Rs[i] = root2[i];
  for (int i = threadIdx.x; i < NG * H2D; i += TPB) Gs[i] = 0.f;
  if (threadIdx.x < H2D) Bs[threadIdx.x] = b2[threadIdx.x];
  if (threadIdx.x < NG) Gc[threadIdx.x] = 0.f;
  __syncthreads();

  int n = blockIdx.x * (TPB / 16) + (threadIdx.x >> 4);
  int j = threadIdx.x & 15;
  int start = rowptr[n];
  int dg = deg[n];

  float a0 = 0.f, a1 = 0.f;
  for (int k = 0; k < dg; ++k) {
    unsigned key = keys[start + k];
    int s = key & 0x3FFFF;
    int r = key >> 18;
    float norm = 1.f / (float)counts[r * NN + n];
    float hv = h1[s * H1D + j];
    float m0 = 0.f, m1 = 0.f;
    const float* Wr = &Ws[r * 513 + j];
#pragma unroll
    for (int i = 0; i < H1D; ++i) {
      float hi = __shfl(hv, i, 16);
      m0 = fmaf(hi, Wr[i * H2D], m0);
      m1 = fmaf(hi, Wr[i * H2D + 16], m1);
    }
    a0 = fmaf(m0, norm, a0);
    a1 = fmaf(m1, norm, a1);
  }

  float hn = h1[n * H1D + j];
  float c0 = Bs[j] + a0, c1 = Bs[j + 16] + a1;
#pragma unroll
  for (int i = 0; i < H1D; ++i) {
    float hi = __shfl(hn, i, 16);
    c0 = fmaf(hi, Rs[i * H2D + j], c0);
    c1 = fmaf(hi, Rs[i * H2D + j + 16], c1);
  }
  c0 = fmaxf(c0, 0.f);
  c1 = fmaxf(c1, 0.f);

  int g = batch[n];
  atomicAdd(&Gs[g * H2D + j], c0);
  atomicAdd(&Gs[g * H2D + 16 + j], c1);
  if (j == 0) atomicAdd(&Gc[g], 1.f);
  __syncthreads();

  // flush nonzero partials (block spans ~2 graphs since batch is sorted)
  for (int i = threadIdx.x; i < NG * H2D; i += TPB) {
    float v = Gs[i];
    if (v != 0.f) atomicAdd(&gsum[i], v);
  }
  for (int i = threadIdx.x; i < NG; i += TPB) {
    float v = Gc[i];
    if (v != 0.f) atomicAdd(&gcnt[i], v);
  }
}

// ---------------- k9: final head ----------------
__global__ __launch_bounds__(128) void final_kernel(
    const float* __restrict__ gsum, const float* __restrict__ gcnt,
    const float* __restrict__ fcW, const float* __restrict__ fcb,
    float* __restrict__ out) {
  int t = threadIdx.x;
  if (t >= NG * NC) return;
  int g = t >> 1, c = t & 1;
  float cnt = fmaxf(gcnt[g], 1.0f);
  float acc = fcb[c];
#pragma unroll
  for (int j = 0; j < H2D; ++j)
    acc = fmaf(gsum[g * H2D + j] / cnt, fcW[j * NC + c], acc);
  out[t] = acc;
}

}  // namespace

extern "C" void kernel_launch(void* const* d_in, const int* in_sizes, int n_in,
                              void* d_out, int out_size, void* d_ws, size_t ws_size,
                              hipStream_t stream) {
  (void)in_sizes; (void)n_in; (void)out_size; (void)ws_size;

  const float* x     = (const float*)d_in[0];
  const int*   ei    = (const int*)d_in[1];
  const int*   etype = (const int*)d_in[2];
  const int*   batch = (const int*)d_in[3];
  const float* W1    = (const float*)d_in[4];
  const float* root1 = (const float*)d_in[5];
  const float* b1    = (const float*)d_in[6];
  const float* W2    = (const float*)d_in[7];
  const float* root2 = (const float*)d_in[8];
  const float* b2    = (const float*)d_in[9];
  const float* fcW   = (const float*)d_in[10];
  const float* fcb   = (const float*)d_in[11];

  const int* src = ei;
  const int* dst = ei + NE;

  // workspace layout (bytes)
  char* ws = (char*)d_ws;
  int*      counts = (int*)(ws + 0);                 // 16,000,000
  int*      cursor = (int*)(ws + 16000000);          //    800,000
  float*    gsum   = (float*)(ws + 16800000);        //      8,192
  float*    gcnt   = (float*)(ws + 16808192);        //        256
  // ---- end of zeroed region (16,808,448 B) ----
  int*      deg    = (int*)(ws + 16808448);          //    800,000
  int*      rowptr = (int*)(ws + 17608448);          //    800,000
  int*      bsum   = (int*)(ws + 18408448);          //      4,096
  int*      bofs   = (int*)(ws + 18412544);          //      4,096
  unsigned* keys   = (unsigned*)(ws + 18416640);     // 12,800,000
  float*    h1     = (float*)(ws + 31216640);        // 12,800,000
  // total: 44,016,640 B

  hipMemsetAsync(ws, 0, 16808448, stream);

  int egrid = (NE + TPB - 1) / TPB;   // 12500
  int ggrid = NN / (TPB / 16);        // 12500 (exact: 12500*16 == NN)

  count_kernel<<<egrid, TPB, 0, stream>>>(etype, dst, counts);
  deg_kernel<<<NB, TPB, 0, stream>>>(counts, deg);
  scan1_kernel<<<NB, TPB, 0, stream>>>(deg, rowptr, bsum);
  scan2_kernel<<<1, 1024, 0, stream>>>(bsum, bofs);
  scan3_kernel<<<NB, TPB, 0, stream>>>(rowptr, bofs);
  scatter_kernel<<<egrid, TPB, 0, stream>>>(src, dst, etype, rowptr, cursor, keys);
  gather1_kernel<<<ggrid, TPB, 0, stream>>>(x, keys, rowptr, deg, counts, W1, root1, b1, h1);
  gather2_kernel<<<ggrid, TPB, 0, stream>>>(h1, keys, rowptr, deg, counts, W2, root2, b2, batch, gsum, gcnt);
  final_kernel<<<1, 128, 0, stream>>>(gsum, gcnt, fcW, fcb, (float*)d_out);
}

// Round 4
// 887.537 us; speedup vs baseline: 9.0883x; 1.2849x over previous
//
#include <hip/hip_runtime.h>

namespace {

constexpr int NN  = 200000;   // nodes
constexpr int NE  = 3200000;  // edges
constexpr int NR  = 20;       // relations
constexpr int FIN = 16;
constexpr int H1D = 16;
constexpr int H2D = 32;
constexpr int NC  = 2;
constexpr int NG  = 64;

constexpr int TPB = 256;
constexpr int NB  = (NN + TPB - 1) / TPB;  // 782

// W1T layout: [r][j][i], j-row stride 20 floats (80 B, 16B-aligned, <=2-way banks),
// relation stride 16*20+4 = 324 floats (per-r bank shift)
constexpr int W1_JS = 20, W1_RS = 324;
// W2P layout: [r][j][pair(i)], element = {W[i][j], W[i][j+16]}; j-row stride 36 floats
// (144 B aligned), relation stride 16*36+4 = 580 floats
constexpr int W2_JS = 36, W2_RS = 580;

// ---------------- k1: per-(relation,dst) in-degree counts ----------------
__global__ __launch_bounds__(TPB) void count_kernel(
    const int* __restrict__ etype, const int* __restrict__ dst,
    int* __restrict__ counts) {
  int e = blockIdx.x * TPB + threadIdx.x;
  if (e < NE) atomicAdd(&counts[etype[e] * NN + dst[e]], 1);
}

// ---------------- k2: total in-degree per node ----------------
__global__ __launch_bounds__(TPB) void deg_kernel(
    const int* __restrict__ counts, int* __restrict__ deg) {
  int d = blockIdx.x * TPB + threadIdx.x;
  if (d >= NN) return;
  int s = 0;
#pragma unroll
  for (int r = 0; r < NR; ++r) s += counts[r * NN + d];
  deg[d] = s;
}

// ---------------- k3/k4/k5: exclusive scan of deg -> rowptr ----------------
__global__ __launch_bounds__(TPB) void scan1_kernel(
    const int* __restrict__ deg, int* __restrict__ excl, int* __restrict__ bsum) {
  __shared__ int s[TPB];
  int tid = threadIdx.x;
  int i = blockIdx.x * TPB + tid;
  int v = (i < NN) ? deg[i] : 0;
  s[tid] = v;
  __syncthreads();
  for (int off = 1; off < TPB; off <<= 1) {
    int t = 0;
    if (tid >= off) t = s[tid - off];
    __syncthreads();
    if (tid >= off) s[tid] += t;
    __syncthreads();
  }
  if (i < NN) excl[i] = s[tid] - v;
  if (tid == TPB - 1) bsum[blockIdx.x] = s[tid];
}

__global__ __launch_bounds__(1024) void scan2_kernel(
    const int* __restrict__ bsum, int* __restrict__ bofs) {
  __shared__ int s[1024];
  int tid = threadIdx.x;
  int v = (tid < NB) ? bsum[tid] : 0;
  s[tid] = v;
  __syncthreads();
  for (int off = 1; off < 1024; off <<= 1) {
    int t = 0;
    if (tid >= off) t = s[tid - off];
    __syncthreads();
    if (tid >= off) s[tid] += t;
    __syncthreads();
  }
  if (tid < NB) bofs[tid] = s[tid] - v;
}

__global__ __launch_bounds__(TPB) void scan3_kernel(
    int* __restrict__ rowptr, const int* __restrict__ bofs) {
  int i = blockIdx.x * TPB + threadIdx.x;
  if (i < NN) rowptr[i] += bofs[blockIdx.x];
}

// ---------------- k6: scatter edges into dst-sorted key array + per-edge norm ----------------
__global__ __launch_bounds__(TPB) void scatter_kernel(
    const int* __restrict__ src, const int* __restrict__ dst,
    const int* __restrict__ etype, const int* __restrict__ rowptr,
    const int* __restrict__ counts,
    int* __restrict__ cursor, unsigned* __restrict__ keys,
    float* __restrict__ normv) {
  int e = blockIdx.x * TPB + threadIdx.x;
  if (e >= NE) return;
  int d = dst[e];
  int r = etype[e];
  int pos = rowptr[d] + atomicAdd(&cursor[d], 1);
  keys[pos] = (unsigned)src[e] | ((unsigned)r << 18);
  normv[pos] = 1.0f / (float)counts[r * NN + d];
}

// ---------------- k7: layer-1 gather (16-lane groups, lane = out channel) ----------------
__global__ __launch_bounds__(512, 6) void gather1_kernel(
    const float* __restrict__ x, const unsigned* __restrict__ keys,
    const float* __restrict__ normv,
    const int* __restrict__ rowptr, const int* __restrict__ deg,
    const float* __restrict__ W1, const float* __restrict__ root1,
    const float* __restrict__ b1, float* __restrict__ h1) {
  __shared__ float Ws[NR * W1_RS];   // ~25.9 KB
  __shared__ float Rs[H1D * W1_JS];  // root1 transposed, 1.28 KB
  __shared__ float Bs[H1D];
  for (int idx = threadIdx.x; idx < NR * 256; idx += 512) {
    int r = idx >> 8, rem = idx & 255, i = rem >> 4, j = rem & 15;
    Ws[r * W1_RS + j * W1_JS + i] = W1[idx];
  }
  for (int idx = threadIdx.x; idx < 256; idx += 512) {
    int i = idx >> 4, j = idx & 15;
    Rs[j * W1_JS + i] = root1[idx];
  }
  if (threadIdx.x < H1D) Bs[threadIdx.x] = b1[threadIdx.x];
  __syncthreads();

  int n = blockIdx.x * 32 + (threadIdx.x >> 4);  // 6250*32 == NN exact
  int j = threadIdx.x & 15;
  int start = rowptr[n];
  int kend = start + deg[n];

  float agg = 0.f;
  unsigned key = keys[min(start, NE - 1)];
  float nv = normv[min(start, NE - 1)];
  for (int k = start; k < kend; ++k) {
    int s = key & 0x3FFFF;
    float nvc = nv;
    // source row: same address across the 16-lane group -> cache broadcast
    const float4* xr = (const float4*)(x + s * FIN);
    float4 x0 = xr[0], x1 = xr[1], x2 = xr[2], x3 = xr[3];
    const float4* Wr = (const float4*)&Ws[(key >> 18) * W1_RS + j * W1_JS];
    // prefetch next edge meta
    int nk = min(k + 1, NE - 1);
    key = keys[nk];
    nv = normv[nk];
    float4 w0 = Wr[0], w1 = Wr[1], w2 = Wr[2], w3 = Wr[3];
    float m = 0.f;
    m = fmaf(x0.x, w0.x, m); m = fmaf(x0.y, w0.y, m);
    m = fmaf(x0.z, w0.z, m); m = fmaf(x0.w, w0.w, m);
    m = fmaf(x1.x, w1.x, m); m = fmaf(x1.y, w1.y, m);
    m = fmaf(x1.z, w1.z, m); m = fmaf(x1.w, w1.w, m);
    m = fmaf(x2.x, w2.x, m); m = fmaf(x2.y, w2.y, m);
    m = fmaf(x2.z, w2.z, m); m = fmaf(x2.w, w2.w, m);
    m = fmaf(x3.x, w3.x, m); m = fmaf(x3.y, w3.y, m);
    m = fmaf(x3.z, w3.z, m); m = fmaf(x3.w, w3.w, m);
    agg = fmaf(m, nvc, agg);
  }

  // root transform + bias + relu
  const float4* xr = (const float4*)(x + n * FIN);
  float4 x0 = xr[0], x1 = xr[1], x2 = xr[2], x3 = xr[3];
  const float4* Rr = (const float4*)&Rs[j * W1_JS];
  float4 r0 = Rr[0], r1 = Rr[1], r2 = Rr[2], r3 = Rr[3];
  float acc = Bs[j] + agg;
  acc = fmaf(x0.x, r0.x, acc); acc = fmaf(x0.y, r0.y, acc);
  acc = fmaf(x0.z, r0.z, acc); acc = fmaf(x0.w, r0.w, acc);
  acc = fmaf(x1.x, r1.x, acc); acc = fmaf(x1.y, r1.y, acc);
  acc = fmaf(x1.z, r1.z, acc); acc = fmaf(x1.w, r1.w, acc);
  acc = fmaf(x2.x, r2.x, acc); acc = fmaf(x2.y, r2.y, acc);
  acc = fmaf(x2.z, r2.z, acc); acc = fmaf(x2.w, r2.w, acc);
  acc = fmaf(x3.x, r3.x, acc); acc = fmaf(x3.y, r3.y, acc);
  acc = fmaf(x3.z, r3.z, acc); acc = fmaf(x3.w, r3.w, acc);
  h1[n * H1D + j] = fmaxf(acc, 0.f);
}

// ---------------- k8: layer-2 gather (16-lane groups, lane = channels j, j+16) ----------------
__global__ __launch_bounds__(512, 6) void gather2_kernel(
    const float* __restrict__ h1, const unsigned* __restrict__ keys,
    const float* __restrict__ normv,
    const int* __restrict__ rowptr, const int* __restrict__ deg,
    const float* __restrict__ W2, const float* __restrict__ root2,
    const float* __restrict__ b2, float* __restrict__ h2) {
  __shared__ float Ws[NR * W2_RS];   // ~46.4 KB
  __shared__ float Rs[H1D * W2_JS];  // root2 paired, 2.3 KB
  __shared__ float Bs[H2D];
  for (int idx = threadIdx.x; idx < NR * 512; idx += 512) {
    int r = idx >> 9, rem = idx & 511, i = rem >> 5, jj = rem & 31;
    Ws[r * W2_RS + (jj & 15) * W2_JS + i * 2 + (jj >> 4)] = W2[idx];
  }
  for (int idx = threadIdx.x; idx < 512; idx += 512) {
    int i = idx >> 5, jj = idx & 31;
    Rs[(jj & 15) * W2_JS + i * 2 + (jj >> 4)] = root2[idx];
  }
  if (threadIdx.x < H2D) Bs[threadIdx.x] = b2[threadIdx.x];
  __syncthreads();

  int n = blockIdx.x * 32 + (threadIdx.x >> 4);
  int j = threadIdx.x & 15;
  int start = rowptr[n];
  int kend = start + deg[n];

  float a0 = 0.f, a1 = 0.f;
  unsigned key = keys[min(start, NE - 1)];
  float nv = normv[min(start, NE - 1)];
  for (int k = start; k < kend; ++k) {
    int s = key & 0x3FFFF;
    float nvc = nv;
    const float4* hr = (const float4*)(h1 + s * H1D);
    float4 x0 = hr[0], x1 = hr[1], x2 = hr[2], x3 = hr[3];
    const float4* Wr = (const float4*)&Ws[(key >> 18) * W2_RS + j * W2_JS];
    int nk = min(k + 1, NE - 1);
    key = keys[nk];
    nv = normv[nk];
    float m0 = 0.f, m1 = 0.f;
    float4 w;
    w = Wr[0]; m0 = fmaf(x0.x, w.x, m0); m1 = fmaf(x0.x, w.y, m1);
               m0 = fmaf(x0.y, w.z, m0); m1 = fmaf(x0.y, w.w, m1);
    w = Wr[1]; m0 = fmaf(x0.z, w.x, m0); m1 = fmaf(x0.z, w.y, m1);
               m0 = fmaf(x0.w, w.z, m0); m1 = fmaf(x0.w, w.w, m1);
    w = Wr[2]; m0 = fmaf(x1.x, w.x, m0); m1 = fmaf(x1.x, w.y, m1);
               m0 = fmaf(x1.y, w.z, m0); m1 = fmaf(x1.y, w.w, m1);
    w = Wr[3]; m0 = fmaf(x1.z, w.x, m0); m1 = fmaf(x1.z, w.y, m1);
               m0 = fmaf(x1.w, w.z, m0); m1 = fmaf(x1.w, w.w, m1);
    w = Wr[4]; m0 = fmaf(x2.x, w.x, m0); m1 = fmaf(x2.x, w.y, m1);
               m0 = fmaf(x2.y, w.z, m0); m1 = fmaf(x2.y, w.w, m1);
    w = Wr[5]; m0 = fmaf(x2.z, w.x, m0); m1 = fmaf(x2.z, w.y, m1);
               m0 = fmaf(x2.w, w.z, m0); m1 = fmaf(x2.w, w.w, m1);
    w = Wr[6]; m0 = fmaf(x3.x, w.x, m0); m1 = fmaf(x3.x, w.y, m1);
               m0 = fmaf(x3.y, w.z, m0); m1 = fmaf(x3.y, w.w, m1);
    w = Wr[7]; m0 = fmaf(x3.z, w.x, m0); m1 = fmaf(x3.z, w.y, m1);
               m0 = fmaf(x3.w, w.z, m0); m1 = fmaf(x3.w, w.w, m1);
    a0 = fmaf(m0, nvc, a0);
    a1 = fmaf(m1, nvc, a1);
  }

  const float4* hr = (const float4*)(h1 + n * H1D);
  float4 x0 = hr[0], x1 = hr[1], x2 = hr[2], x3 = hr[3];
  const float4* Rr = (const float4*)&Rs[j * W2_JS];
  float c0 = Bs[j] + a0, c1 = Bs[j + 16] + a1;
  float4 w;
  w = Rr[0]; c0 = fmaf(x0.x, w.x, c0); c1 = fmaf(x0.x, w.y, c1);
             c0 = fmaf(x0.y, w.z, c0); c1 = fmaf(x0.y, w.w, c1);
  w = Rr[1]; c0 = fmaf(x0.z, w.x, c0); c1 = fmaf(x0.z, w.y, c1);
             c0 = fmaf(x0.w, w.z, c0); c1 = fmaf(x0.w, w.w, c1);
  w = Rr[2]; c0 = fmaf(x1.x, w.x, c0); c1 = fmaf(x1.x, w.y, c1);
             c0 = fmaf(x1.y, w.z, c0); c1 = fmaf(x1.y, w.w, c1);
  w = Rr[3]; c0 = fmaf(x1.z, w.x, c0); c1 = fmaf(x1.z, w.y, c1);
             c0 = fmaf(x1.w, w.z, c0); c1 = fmaf(x1.w, w.w, c1);
  w = Rr[4]; c0 = fmaf(x2.x, w.x, c0); c1 = fmaf(x2.x, w.y, c1);
             c0 = fmaf(x2.y, w.z, c0); c1 = fmaf(x2.y, w.w, c1);
  w = Rr[5]; c0 = fmaf(x2.z, w.x, c0); c1 = fmaf(x2.z, w.y, c1);
             c0 = fmaf(x2.w, w.z, c0); c1 = fmaf(x2.w, w.w, c1);
  w = Rr[6]; c0 = fmaf(x3.x, w.x, c0); c1 = fmaf(x3.x, w.y, c1);
             c0 = fmaf(x3.y, w.z, c0); c1 = fmaf(x3.y, w.w, c1);
  w = Rr[7]; c0 = fmaf(x3.z, w.x, c0); c1 = fmaf(x3.z, w.y, c1);
             c0 = fmaf(x3.w, w.z, c0); c1 = fmaf(x3.w, w.w, c1);
  h2[n * H2D + j] = fmaxf(c0, 0.f);
  h2[n * H2D + 16 + j] = fmaxf(c1, 0.f);
}

// ---------------- k9: graph mean-pool partials ----------------
__global__ __launch_bounds__(TPB) void pool_kernel(
    const float* __restrict__ h2, const int* __restrict__ batch,
    float* __restrict__ gsum, float* __restrict__ gcnt) {
  __shared__ float Gs[8 * H2D];
  __shared__ float Gc[8];
  __shared__ int Bb[TPB];
  int tid = threadIdx.x;
  int base = blockIdx.x * TPB;
  if (tid < 8) Gc[tid] = 0.f;
  if (tid < 8 * H2D) Gs[tid] = 0.f;
  int n = base + tid;
  int g = (n < NN) ? batch[n] : -1;
  Bb[tid] = g;
  __syncthreads();
  int gmin = Bb[0];  // batch sorted ascending
  if (n < NN) {
    int gg = g - gmin;
    if (gg < 8) atomicAdd(&Gc[gg], 1.f);
    else atomicAdd(&gcnt[g], 1.f);   // never-taken fallback (tiny graphs)
  }
  for (int i = tid; i < TPB * H2D; i += TPB) {
    int nl = i >> 5, j = i & 31;
    int nn = base + nl;
    if (nn < NN) {
      int gg = Bb[nl] - gmin;
      float v = h2[nn * H2D + j];
      if (gg < 8) atomicAdd(&Gs[gg * H2D + j], v);
      else atomicAdd(&gsum[Bb[nl] * H2D + j], v);
    }
  }
  __syncthreads();
  if (tid < 8 * H2D) {
    float v = Gs[tid];
    int g2 = gmin + (tid >> 5);
    if (v != 0.f && g2 < NG) atomicAdd(&gsum[g2 * H2D + (tid & 31)], v);
  }
  if (tid < 8) {
    float v = Gc[tid];
    if (v != 0.f && gmin + tid < NG) atomicAdd(&gcnt[gmin + tid], v);
  }
}

// ---------------- k10: final head ----------------
__global__ __launch_bounds__(128) void final_kernel(
    const float* __restrict__ gsum, const float* __restrict__ gcnt,
    const float* __restrict__ fcW, const float* __restrict__ fcb,
    float* __restrict__ out) {
  int t = threadIdx.x;
  if (t >= NG * NC) return;
  int g = t >> 1, c = t & 1;
  float cnt = fmaxf(gcnt[g], 1.0f);
  float acc = fcb[c];
#pragma unroll
  for (int j = 0; j < H2D; ++j)
    acc = fmaf(gsum[g * H2D + j] / cnt, fcW[j * NC + c], acc);
  out[t] = acc;
}

}  // namespace

extern "C" void kernel_launch(void* const* d_in, const int* in_sizes, int n_in,
                              void* d_out, int out_size, void* d_ws, size_t ws_size,
                              hipStream_t stream) {
  (void)in_sizes; (void)n_in; (void)out_size; (void)ws_size;

  const float* x     = (const float*)d_in[0];
  const int*   ei    = (const int*)d_in[1];
  const int*   etype = (const int*)d_in[2];
  const int*   batch = (const int*)d_in[3];
  const float* W1    = (const float*)d_in[4];
  const float* root1 = (const float*)d_in[5];
  const float* b1    = (const float*)d_in[6];
  const float* W2    = (const float*)d_in[7];
  const float* root2 = (const float*)d_in[8];
  const float* b2    = (const float*)d_in[9];
  const float* fcW   = (const float*)d_in[10];
  const float* fcb   = (const float*)d_in[11];

  const int* src = ei;
  const int* dst = ei + NE;

  // workspace layout (bytes); h2 (25.6 MB) aliases counts+cursor (dead after scatter)
  char* ws = (char*)d_ws;
  int*      counts = (int*)(ws + 0);                 // 16,000,000
  int*      cursor = (int*)(ws + 16000000);          //    800,000
  float*    h2     = (float*)(ws + 0);               // 25,600,000 (alias, used after scatter)
  int*      deg    = (int*)(ws + 25600000);          //    800,000
  int*      rowptr = (int*)(ws + 26400000);          //    800,000
  int*      bsum   = (int*)(ws + 27200000);          //      4,096
  int*      bofs   = (int*)(ws + 27204096);          //      4,096
  float*    gsum   = (float*)(ws + 27208192);        //      8,192
  float*    gcnt   = (float*)(ws + 27216384);        //        256
  unsigned* keys   = (unsigned*)(ws + 27216640);     // 12,800,000
  float*    normv  = (float*)(ws + 40016640);        // 12,800,000
  float*    h1     = (float*)(ws + 52816640);        // 12,800,000
  // total: 65,616,640

  hipMemsetAsync(ws, 0, 16800000, stream);           // counts + cursor
  hipMemsetAsync(ws + 27208192, 0, 8448, stream);    // gsum + gcnt

  int egrid = (NE + TPB - 1) / TPB;   // 12500
  int ggrid = NN / 32;                // 6250 (exact: 6250*32 == NN)

  count_kernel<<<egrid, TPB, 0, stream>>>(etype, dst, counts);
  deg_kernel<<<NB, TPB, 0, stream>>>(counts, deg);
  scan1_kernel<<<NB, TPB, 0, stream>>>(deg, rowptr, bsum);
  scan2_kernel<<<1, 1024, 0, stream>>>(bsum, bofs);
  scan3_kernel<<<NB, TPB, 0, stream>>>(rowptr, bofs);
  scatter_kernel<<<egrid, TPB, 0, stream>>>(src, dst, etype, rowptr, counts, cursor, keys, normv);
  gather1_kernel<<<ggrid, 512, 0, stream>>>(x, keys, normv, rowptr, deg, W1, root1, b1, h1);
  gather2_kernel<<<ggrid, 512, 0, stream>>>(h1, keys, normv, rowptr, deg, W2, root2, b2, h2);
  pool_kernel<<<NB, TPB, 0, stream>>>(h2, batch, gsum, gcnt);
  final_kernel<<<1, 128, 0, stream>>>(gsum, gcnt, fcW, fcb, (float*)d_out);
}

// Round 6
// 839.409 us; speedup vs baseline: 9.6094x; 1.0573x over previous
//
#include <hip/hip_runtime.h>

namespace {

constexpr int NN  = 200000;   // nodes
constexpr int NE  = 3200000;  // edges
constexpr int NR  = 20;       // relations
constexpr int FIN = 16;
constexpr int H1D = 16;
constexpr int H2D = 32;
constexpr int NC  = 2;
constexpr int NG  = 64;
constexpr int NP  = NN * NR;  // 4,000,000 (dst-major pair index p = d*NR + r)

constexpr int TPB = 256;
constexpr int NB  = (NN + TPB - 1) / TPB;        // 782
constexpr int S1B = (NP + 1023) / 1024;          // 3907 scan level-1 blocks

// gather1 W1 in LDS fp32: [r][j][i], j-stride 20 floats (16B-aligned, bank period 8),
// r-stride 324 floats (mult of 4, +4-bank shift per relation). 25.9 KB.
constexpr int W1_JS = 20, W1_RS = 324;
// gather2 W2 in LDS bf16-pair dwords: dword(i) = {bf16 W[i][j], bf16 W[i][j+16]},
// [r][j][i] with j-stride 20 dwords, r-stride 328 dwords (both mult of 4 -> 16B align;
// 20j mod 32 gives 8 distinct 4-spaced starts -> ~2-way, free). 26.2 KB.
constexpr int W2_JS = 20, W2_RS = 328;
// gather2 root fp32 pair layout [j][2i+sel], stride 36 floats.
constexpr int R2_JS = 36;

__device__ __forceinline__ float bflo(unsigned d) { return __uint_as_float(d << 16); }
__device__ __forceinline__ float bfhi(unsigned d) { return __uint_as_float(d & 0xFFFF0000u); }
__device__ __forceinline__ unsigned short f2bf(float f) {  // round-to-nearest-even
  unsigned u = __float_as_uint(f);
  return (unsigned short)((u + 0x7FFFu + ((u >> 16) & 1u)) >> 16);
}

// ---------------- x -> bf16 prep ----------------
__global__ __launch_bounds__(TPB) void xprep_kernel(
    const float* __restrict__ x, unsigned short* __restrict__ xb) {
  int t = blockIdx.x * TPB + threadIdx.x;         // 800,000 threads, 4 elems each
  if (t >= (NN * FIN) / 4) return;
  float4 v = ((const float4*)x)[t];
  ushort4 o;
  o.x = f2bf(v.x); o.y = f2bf(v.y); o.z = f2bf(v.z); o.w = f2bf(v.w);
  ((ushort4*)xb)[t] = o;
}

// ---------------- per-(dst,relation) pair counts ----------------
__global__ __launch_bounds__(TPB) void count_kernel(
    const int* __restrict__ etype, const int* __restrict__ dst,
    int* __restrict__ counts) {
  int e = blockIdx.x * TPB + threadIdx.x;
  if (e < NE) atomicAdd(&counts[dst[e] * NR + etype[e]], 1);
}

// ---------------- 2-level scan over 4M pair counts -> pairbase ----------------
__global__ __launch_bounds__(TPB) void scan1_kernel(
    const int* __restrict__ cnt, int* __restrict__ pb, int* __restrict__ bsum) {
  __shared__ int s[TPB];
  int tid = threadIdx.x;
  int base = blockIdx.x * 1024 + tid * 4;
  int v0 = (base + 0 < NP) ? cnt[base + 0] : 0;
  int v1 = (base + 1 < NP) ? cnt[base + 1] : 0;
  int v2 = (base + 2 < NP) ? cnt[base + 2] : 0;
  int v3 = (base + 3 < NP) ? cnt[base + 3] : 0;
  int tot = v0 + v1 + v2 + v3;
  s[tid] = tot;
  __syncthreads();
  for (int off = 1; off < TPB; off <<= 1) {
    int t = 0;
    if (tid >= off) t = s[tid - off];
    __syncthreads();
    if (tid >= off) s[tid] += t;
    __syncthreads();
  }
  int excl = s[tid] - tot;
  if (base + 0 < NP) pb[base + 0] = excl;
  if (base + 1 < NP) pb[base + 1] = excl + v0;
  if (base + 2 < NP) pb[base + 2] = excl + v0 + v1;
  if (base + 3 < NP) pb[base + 3] = excl + v0 + v1 + v2;
  if (tid == TPB - 1) bsum[blockIdx.x] = s[tid];
}

__global__ __launch_bounds__(1024) void scan2_kernel(
    const int* __restrict__ bsum, int* __restrict__ bofs) {
  __shared__ int s[1024];
  int tid = threadIdx.x;
  int base = tid * 4;
  int v0 = (base + 0 < S1B) ? bsum[base + 0] : 0;
  int v1 = (base + 1 < S1B) ? bsum[base + 1] : 0;
  int v2 = (base + 2 < S1B) ? bsum[base + 2] : 0;
  int v3 = (base + 3 < S1B) ? bsum[base + 3] : 0;
  int tot = v0 + v1 + v2 + v3;
  s[tid] = tot;
  __syncthreads();
  for (int off = 1; off < 1024; off <<= 1) {
    int t = 0;
    if (tid >= off) t = s[tid - off];
    __syncthreads();
    if (tid >= off) s[tid] += t;
    __syncthreads();
  }
  int excl = s[tid] - tot;
  if (base + 0 < S1B) bofs[base + 0] = excl;
  if (base + 1 < S1B) bofs[base + 1] = excl + v0;
  if (base + 2 < S1B) bofs[base + 2] = excl + v0 + v1;
  if (base + 3 < S1B) bofs[base + 3] = excl + v0 + v1 + v2;
}

__global__ __launch_bounds__(TPB) void scan3_kernel(
    int* __restrict__ pb, const int* __restrict__ bofs) {
  int i = blockIdx.x * TPB + threadIdx.x;
  if (i < NP) pb[i] += bofs[i >> 10];
}

// ---------------- scatter edges into (dst,relation)-sorted keys ----------------
// reuses counts[] as a countdown cursor (atomicSub); order within a pair is irrelevant
__global__ __launch_bounds__(TPB) void scatter_kernel(
    const int* __restrict__ src, const int* __restrict__ dst,
    const int* __restrict__ etype, const int* __restrict__ pb,
    int* __restrict__ cnt, unsigned* __restrict__ keys) {
  int e = blockIdx.x * TPB + threadIdx.x;
  if (e >= NE) return;
  int r = etype[e];
  int p = dst[e] * NR + r;
  int slot = atomicSub(&cnt[p], 1) - 1;
  keys[pb[p] + slot] = (unsigned)src[e] | ((unsigned)r << 18);
}

// ---------------- layer-1 gather (16-lane groups, lane = out channel) ----------------
// edges are r-sorted per node -> mean norm computed at run boundaries (no normv array)
__global__ __launch_bounds__(512, 8) void gather1_kernel(
    const float* __restrict__ x, const unsigned short* __restrict__ xb,
    const unsigned* __restrict__ keys, const int* __restrict__ pb,
    const float* __restrict__ W1, const float* __restrict__ root1,
    const float* __restrict__ b1, unsigned short* __restrict__ h1) {
  __shared__ float Ws[NR * W1_RS];   // 25.9 KB
  __shared__ float Rs[H1D * W1_JS];
  __shared__ float Bs[H1D];
  for (int idx = threadIdx.x; idx < NR * 256; idx += 512) {
    int r = idx >> 8, rem = idx & 255, i = rem >> 4, j = rem & 15;
    Ws[r * W1_RS + j * W1_JS + i] = W1[idx];
  }
  for (int idx = threadIdx.x; idx < 256; idx += 512) {
    int i = idx >> 4, j = idx & 15;
    Rs[j * W1_JS + i] = root1[idx];
  }
  if (threadIdx.x < H1D) Bs[threadIdx.x] = b1[threadIdx.x];
  __syncthreads();

  int n = blockIdx.x * 32 + (threadIdx.x >> 4);   // 6250*32 == NN exact
  int j = threadIdx.x & 15;
  int start = pb[n * NR];
  int end   = (n == NN - 1) ? NE : pb[(n + 1) * NR];

  float agg = 0.f, msum = 0.f, cntf = 0.f;
  unsigned key = 0;
  uint4 ra = {0, 0, 0, 0}, rb = {0, 0, 0, 0};
  if (start < end) {
    key = keys[start];
    const uint4* rp = (const uint4*)(xb + (size_t)(key & 0x3FFFFu) * FIN);
    ra = rp[0]; rb = rp[1];
  }
  for (int k = start; k < end; ++k) {
    unsigned r = key >> 18;
    uint4 ca = ra, cb = rb;
    unsigned nkey = 0xFFFFFFFFu;                  // sentinel r -> forces final boundary
    if (k + 1 < end) {
      nkey = keys[k + 1];
      const uint4* rp = (const uint4*)(xb + (size_t)(nkey & 0x3FFFFu) * FIN);
      ra = rp[0]; rb = rp[1];
    }
    const float4* Wr = (const float4*)&Ws[r * W1_RS + j * W1_JS];
    float4 w0 = Wr[0], w1 = Wr[1], w2 = Wr[2], w3 = Wr[3];
    float m = 0.f;
    m = fmaf(bflo(ca.x), w0.x, m); m = fmaf(bfhi(ca.x), w0.y, m);
    m = fmaf(bflo(ca.y), w0.z, m); m = fmaf(bfhi(ca.y), w0.w, m);
    m = fmaf(bflo(ca.z), w1.x, m); m = fmaf(bfhi(ca.z), w1.y, m);
    m = fmaf(bflo(ca.w), w1.z, m); m = fmaf(bfhi(ca.w), w1.w, m);
    m = fmaf(bflo(cb.x), w2.x, m); m = fmaf(bfhi(cb.x), w2.y, m);
    m = fmaf(bflo(cb.y), w2.z, m); m = fmaf(bfhi(cb.y), w2.w, m);
    m = fmaf(bflo(cb.z), w3.x, m); m = fmaf(bfhi(cb.z), w3.y, m);
    m = fmaf(bflo(cb.w), w3.z, m); m = fmaf(bfhi(cb.w), w3.w, m);
    msum += m; cntf += 1.f;
    if ((nkey >> 18) != r) {                      // relation-run boundary
      agg = fmaf(msum, 1.0f / cntf, agg);
      msum = 0.f; cntf = 0.f;
    }
    key = nkey;
  }

  // root transform (fp32 x) + bias + relu -> bf16 h1
  const float4* xr = (const float4*)(x + (size_t)n * FIN);
  float4 x0 = xr[0], x1 = xr[1], x2 = xr[2], x3 = xr[3];
  const float4* Rr = (const float4*)&Rs[j * W1_JS];
  float4 r0 = Rr[0], r1 = Rr[1], r2 = Rr[2], r3 = Rr[3];
  float acc = Bs[j] + agg;
  acc = fmaf(x0.x, r0.x, acc); acc = fmaf(x0.y, r0.y, acc);
  acc = fmaf(x0.z, r0.z, acc); acc = fmaf(x0.w, r0.w, acc);
  acc = fmaf(x1.x, r1.x, acc); acc = fmaf(x1.y, r1.y, acc);
  acc = fmaf(x1.z, r1.z, acc); acc = fmaf(x1.w, r1.w, acc);
  acc = fmaf(x2.x, r2.x, acc); acc = fmaf(x2.y, r2.y, acc);
  acc = fmaf(x2.z, r2.z, acc); acc = fmaf(x2.w, r2.w, acc);
  acc = fmaf(x3.x, r3.x, acc); acc = fmaf(x3.y, r3.y, acc);
  acc = fmaf(x3.z, r3.z, acc); acc = fmaf(x3.w, r3.w, acc);
  h1[(size_t)n * H1D + j] = f2bf(fmaxf(acc, 0.f));
}

// ---------------- layer-2 gather (16-lane groups, lane = channels j, j+16) ----------------
__global__ __launch_bounds__(512, 8) void gather2_kernel(
    const unsigned short* __restrict__ h1, const unsigned* __restrict__ keys,
    const int* __restrict__ pb, const float* __restrict__ W2,
    const float* __restrict__ root2, const float* __restrict__ b2,
    unsigned short* __restrict__ h2) {
  __shared__ unsigned Wsu[NR * W2_RS];  // bf16 pairs, 26.2 KB
  __shared__ float Rs[H1D * R2_JS];
  __shared__ float Bs[H2D];
  for (int idx = threadIdx.x; idx < NR * 256; idx += 512) {
    int r = idx >> 8, rem = idx & 255, j = rem >> 4, i = rem & 15;
    float lo = W2[r * 512 + i * 32 + j];
    float hi = W2[r * 512 + i * 32 + j + 16];
    Wsu[r * W2_RS + j * W2_JS + i] = (unsigned)f2bf(lo) | ((unsigned)f2bf(hi) << 16);
  }
  for (int idx = threadIdx.x; idx < 512; idx += 512) {
    int i = idx >> 5, jj = idx & 31;
    Rs[(jj & 15) * R2_JS + i * 2 + (jj >> 4)] = root2[idx];
  }
  if (threadIdx.x < H2D) Bs[threadIdx.x] = b2[threadIdx.x];
  __syncthreads();

  int n = blockIdx.x * 32 + (threadIdx.x >> 4);
  int j = threadIdx.x & 15;
  int start = pb[n * NR];
  int end   = (n == NN - 1) ? NE : pb[(n + 1) * NR];

  float agg0 = 0.f, agg1 = 0.f, msum0 = 0.f, msum1 = 0.f, cntf = 0.f;
  unsigned key = 0;
  uint4 ra = {0, 0, 0, 0}, rb = {0, 0, 0, 0};
  if (start < end) {
    key = keys[start];
    const uint4* rp = (const uint4*)(h1 + (size_t)(key & 0x3FFFFu) * H1D);
    ra = rp[0]; rb = rp[1];
  }
  for (int k = start; k < end; ++k) {
    unsigned r = key >> 18;
    uint4 ca = ra, cb = rb;
    unsigned nkey = 0xFFFFFFFFu;
    if (k + 1 < end) {
      nkey = keys[k + 1];
      const uint4* rp = (const uint4*)(h1 + (size_t)(nkey & 0x3FFFFu) * H1D);
      ra = rp[0]; rb = rp[1];
    }
    const uint4* Wq = (const uint4*)&Wsu[r * W2_RS + j * W2_JS];
    uint4 q0 = Wq[0], q1 = Wq[1], q2 = Wq[2], q3 = Wq[3];
    float m0 = 0.f, m1 = 0.f;
#define G2STEP(xd, sel, wd) { float xi_ = sel(xd); \
    m0 = fmaf(xi_, bflo(wd), m0); m1 = fmaf(xi_, bfhi(wd), m1); }
    G2STEP(ca.x, bflo, q0.x) G2STEP(ca.x, bfhi, q0.y)
    G2STEP(ca.y, bflo, q0.z) G2STEP(ca.y, bfhi, q0.w)
    G2STEP(ca.z, bflo, q1.x) G2STEP(ca.z, bfhi, q1.y)
    G2STEP(ca.w, bflo, q1.z) G2STEP(ca.w, bfhi, q1.w)
    G2STEP(cb.x, bflo, q2.x) G2STEP(cb.x, bfhi, q2.y)
    G2STEP(cb.y, bflo, q2.z) G2STEP(cb.y, bfhi, q2.w)
    G2STEP(cb.z, bflo, q3.x) G2STEP(cb.z, bfhi, q3.y)
    G2STEP(cb.w, bflo, q3.z) G2STEP(cb.w, bfhi, q3.w)
#undef G2STEP
    msum0 += m0; msum1 += m1; cntf += 1.f;
    if ((nkey >> 18) != r) {
      float nv = 1.0f / cntf;
      agg0 = fmaf(msum0, nv, agg0);
      agg1 = fmaf(msum1, nv, agg1);
      msum0 = 0.f; msum1 = 0.f; cntf = 0.f;
    }
    key = nkey;
  }

  // root transform (bf16 h1 row of node n) + bias + relu -> bf16 h2
  const uint4* hr = (const uint4*)(h1 + (size_t)n * H1D);
  uint4 ha = hr[0], hb = hr[1];
  const float4* Rr = (const float4*)&Rs[j * R2_JS];
  float c0 = Bs[j] + agg0, c1 = Bs[j + 16] + agg1;
  float4 w;
  w = Rr[0]; c0 = fmaf(bflo(ha.x), w.x, c0); c1 = fmaf(bflo(ha.x), w.y, c1);
             c0 = fmaf(bfhi(ha.x), w.z, c0); c1 = fmaf(bfhi(ha.x), w.w, c1);
  w = Rr[1]; c0 = fmaf(bflo(ha.y), w.x, c0); c1 = fmaf(bflo(ha.y), w.y, c1);
             c0 = fmaf(bfhi(ha.y), w.z, c0); c1 = fmaf(bfhi(ha.y), w.w, c1);
  w = Rr[2]; c0 = fmaf(bflo(ha.z), w.x, c0); c1 = fmaf(bflo(ha.z), w.y, c1);
             c0 = fmaf(bfhi(ha.z), w.z, c0); c1 = fmaf(bfhi(ha.z), w.w, c1);
  w = Rr[3]; c0 = fmaf(bflo(ha.w), w.x, c0); c1 = fmaf(bflo(ha.w), w.y, c1);
             c0 = fmaf(bfhi(ha.w), w.z, c0); c1 = fmaf(bfhi(ha.w), w.w, c1);
  w = Rr[4]; c0 = fmaf(bflo(hb.x), w.x, c0); c1 = fmaf(bflo(hb.x), w.y, c1);
             c0 = fmaf(bfhi(hb.x), w.z, c0); c1 = fmaf(bfhi(hb.x), w.w, c1);
  w = Rr[5]; c0 = fmaf(bflo(hb.y), w.x, c0); c1 = fmaf(bflo(hb.y), w.y, c1);
             c0 = fmaf(bfhi(hb.y), w.z, c0); c1 = fmaf(bfhi(hb.y), w.w, c1);
  w = Rr[6]; c0 = fmaf(bflo(hb.z), w.x, c0); c1 = fmaf(bflo(hb.z), w.y, c1);
             c0 = fmaf(bfhi(hb.z), w.z, c0); c1 = fmaf(bfhi(hb.z), w.w, c1);
  w = Rr[7]; c0 = fmaf(bflo(hb.w), w.x, c0); c1 = fmaf(bflo(hb.w), w.y, c1);
             c0 = fmaf(bfhi(hb.w), w.z, c0); c1 = fmaf(bfhi(hb.w), w.w, c1);
  h2[(size_t)n * H2D + j]      = f2bf(fmaxf(c0, 0.f));
  h2[(size_t)n * H2D + 16 + j] = f2bf(fmaxf(c1, 0.f));
}

// ---------------- graph mean-pool partials ----------------
__global__ __launch_bounds__(TPB) void pool_kernel(
    const unsigned short* __restrict__ h2, const int* __restrict__ batch,
    float* __restrict__ gsum, float* __restrict__ gcnt) {
  __shared__ float Gs[8 * H2D];
  __shared__ float Gc[8];
  __shared__ int Bb[TPB];
  int tid = threadIdx.x;
  int base = blockIdx.x * TPB;
  if (tid < 8) Gc[tid] = 0.f;
  if (tid < 8 * H2D) Gs[tid] = 0.f;
  int n = base + tid;
  int g = (n < NN) ? batch[n] : -1;
  Bb[tid] = g;
  __syncthreads();
  int gmin = Bb[0];  // batch sorted ascending
  if (n < NN) {
    int gg = g - gmin;
    if (gg < 8) atomicAdd(&Gc[gg], 1.f);
    else atomicAdd(&gcnt[g], 1.f);
  }
  for (int i = tid; i < TPB * H2D; i += TPB) {
    int nl = i >> 5, j = i & 31;
    int nn = base + nl;
    if (nn < NN) {
      int gg = Bb[nl] - gmin;
      float v = __uint_as_float(((unsigned)h2[(size_t)nn * H2D + j]) << 16);
      if (gg < 8) atomicAdd(&Gs[gg * H2D + j], v);
      else atomicAdd(&gsum[Bb[nl] * H2D + j], v);
    }
  }
  __syncthreads();
  if (tid < 8 * H2D) {
    float v = Gs[tid];
    int g2 = gmin + (tid >> 5);
    if (v != 0.f && g2 < NG) atomicAdd(&gsum[g2 * H2D + (tid & 31)], v);
  }
  if (tid < 8) {
    float v = Gc[tid];
    if (v != 0.f && gmin + tid < NG) atomicAdd(&gcnt[gmin + tid], v);
  }
}

// ---------------- final head ----------------
__global__ __launch_bounds__(128) void final_kernel(
    const float* __restrict__ gsum, const float* __restrict__ gcnt,
    const float* __restrict__ fcW, const float* __restrict__ fcb,
    float* __restrict__ out) {
  int t = threadIdx.x;
  if (t >= NG * NC) return;
  int g = t >> 1, c = t & 1;
  float cnt = fmaxf(gcnt[g], 1.0f);
  float acc = fcb[c];
#pragma unroll
  for (int jj = 0; jj < H2D; ++jj)
    acc = fmaf(gsum[g * H2D + jj] / cnt, fcW[jj * NC + c], acc);
  out[t] = acc;
}

}  // namespace

extern "C" void kernel_launch(void* const* d_in, const int* in_sizes, int n_in,
                              void* d_out, int out_size, void* d_ws, size_t ws_size,
                              hipStream_t stream) {
  (void)in_sizes; (void)n_in; (void)out_size; (void)ws_size;

  const float* x     = (const float*)d_in[0];
  const int*   ei    = (const int*)d_in[1];
  const int*   etype = (const int*)d_in[2];
  const int*   batch = (const int*)d_in[3];
  const float* W1    = (const float*)d_in[4];
  const float* root1 = (const float*)d_in[5];
  const float* b1    = (const float*)d_in[6];
  const float* W2    = (const float*)d_in[7];
  const float* root2 = (const float*)d_in[8];
  const float* b2    = (const float*)d_in[9];
  const float* fcW   = (const float*)d_in[10];
  const float* fcb   = (const float*)d_in[11];

  const int* src = ei;
  const int* dst = ei + NE;

  // workspace layout (bytes); h2 (bf16, 12.8 MB) aliases counts (dead after scatter)
  char* ws = (char*)d_ws;
  int*            counts   = (int*)(ws + 0);                 // 16,000,000
  unsigned short* h2       = (unsigned short*)(ws + 0);      // 12,800,000 (alias)
  int*            pairbase = (int*)(ws + 16000000);          // 16,000,000
  int*            bofs     = (int*)(ws + 32000000);          //     16,384 (3907 ints)
  unsigned*       keys     = (unsigned*)(ws + 32016384);     // 12,800,000
  unsigned short* xb       = (unsigned short*)(ws + 44816384); // 6,400,000
  unsigned short* h1       = (unsigned short*)(ws + 51216384); // 6,400,000
  float*          gsum     = (float*)(ws + 57616384);        //      8,192
  float*          gcnt     = (float*)(ws + 57624576);        //        256
  // total: 57,624,832

  hipMemsetAsync(ws, 0, 16000000, stream);           // counts
  hipMemsetAsync(ws + 57616384, 0, 8448, stream);    // gsum + gcnt

  int egrid = (NE + TPB - 1) / TPB;   // 12500
  int ggrid = NN / 32;                // 6250

  xprep_kernel<<<3125, TPB, 0, stream>>>(x, xb);
  count_kernel<<<egrid, TPB, 0, stream>>>(etype, dst, counts);
  scan1_kernel<<<S1B, TPB, 0, stream>>>(counts, pairbase, bofs + 0);  // bofs reused as bsum
  scan2_kernel<<<1, 1024, 0, stream>>>(bofs, bofs);                   // in-place excl scan
  scan3_kernel<<<(NP + TPB - 1) / TPB, TPB, 0, stream>>>(pairbase, bofs);
  scatter_kernel<<<egrid, TPB, 0, stream>>>(src, dst, etype, pairbase, counts, keys);
  gather1_kernel<<<ggrid, 512, 0, stream>>>(x, xb, keys, pairbase, W1, root1, b1, h1);
  gather2_kernel<<<ggrid, 512, 0, stream>>>(h1, keys, pairbase, W2, root2, b2, h2);
  pool_kernel<<<NB, TPB, 0, stream>>>(h2, batch, gsum, gcnt);
  final_kernel<<<1, 128, 0, stream>>>(gsum, gcnt, fcW, fcb, (float*)d_out);
}

// Round 10
// 812.802 us; speedup vs baseline: 9.9239x; 1.0327x over previous
//
#include <hip/hip_runtime.h>

namespace {

constexpr int NN  = 200000;   // nodes
constexpr int NE  = 3200000;  // edges
constexpr int NR  = 20;       // relations
constexpr int FIN = 16;
constexpr int H1D = 16;
constexpr int H2D = 32;
constexpr int NC  = 2;
constexpr int NG  = 64;
constexpr int NP  = NN * NR;  // 4,000,000 pairs (p = d*NR + r)
constexpr int ND4 = NP / 16;  // 250,000 uint4's of packed u8 counts

constexpr int TPB = 256;
constexpr int NB  = (NN + TPB - 1) / TPB;   // 782
constexpr int S1B = (ND4 + TPB - 1) / TPB;  // 977 scan level-1 blocks (4096 pairs each)

// gather1 W1 LDS fp32: [r][j][i], j-stride 20 floats (80B, 16B-aligned), r-stride 324.
constexpr int W1_JS = 20, W1_RS = 324;      // 25,920 B
// gather2 W2 LDS bf16-pair dwords: dword(i) = {bf16 W[i][j], bf16 W[i][j+16]},
// [r][j][i], j-stride 20 dwords, r-stride 328 dwords. 26,240 B.
constexpr int W2_JS = 20, W2_RS = 328;
constexpr int R2_JS = 36;                   // gather2 root fp32 pair stride

__device__ __forceinline__ float bflo(unsigned d) { return __uint_as_float(d << 16); }
__device__ __forceinline__ float bfhi(unsigned d) { return __uint_as_float(d & 0xFFFF0000u); }
__device__ __forceinline__ unsigned short f2bf(float f) {  // round-to-nearest-even
  unsigned u = __float_as_uint(f);
  return (unsigned short)((u + 0x7FFFu + ((u >> 16) & 1u)) >> 16);
}

// ---------------- x -> bf16 prep ----------------
__global__ __launch_bounds__(TPB) void xprep_kernel(
    const float* __restrict__ x, unsigned short* __restrict__ xb) {
  int t = blockIdx.x * TPB + threadIdx.x;
  if (t >= (NN * FIN) / 4) return;
  float4 v = ((const float4*)x)[t];
  ushort4 o;
  o.x = f2bf(v.x); o.y = f2bf(v.y); o.z = f2bf(v.z); o.w = f2bf(v.w);
  ((ushort4*)xb)[t] = o;
}

// ---------------- per-(dst,relation) counts, u8-packed 4/dword (L2-resident 4MB) ----
__global__ __launch_bounds__(TPB) void count_kernel(
    const int* __restrict__ etype, const int* __restrict__ dst,
    unsigned* __restrict__ cnt) {
  int e = blockIdx.x * TPB + threadIdx.x;
  if (e >= NE) return;
  int p = dst[e] * NR + etype[e];
  atomicAdd(&cnt[p >> 2], 1u << ((p & 3) * 8));
}

// ---------------- scan level 1: 4096 pairs/block -> pb (block-local excl) + bsum ----
__global__ __launch_bounds__(TPB) void scan1_kernel(
    const uint4* __restrict__ cnt4, int* __restrict__ pb, int* __restrict__ bsum) {
  __shared__ int s[TPB];
  int tid = threadIdx.x;
  int idx4 = blockIdx.x * TPB + tid;
  uint4 cd = make_uint4(0, 0, 0, 0);
  if (idx4 < ND4) cd = cnt4[idx4];
  unsigned dws[4] = {cd.x, cd.y, cd.z, cd.w};
  int c[16];
#pragma unroll
  for (int q = 0; q < 4; ++q) {
    c[q * 4 + 0] = dws[q] & 0xFF;
    c[q * 4 + 1] = (dws[q] >> 8) & 0xFF;
    c[q * 4 + 2] = (dws[q] >> 16) & 0xFF;
    c[q * 4 + 3] = dws[q] >> 24;
  }
  int tot = 0;
#pragma unroll
  for (int q = 0; q < 16; ++q) tot += c[q];
  s[tid] = tot;
  __syncthreads();
  for (int off = 1; off < TPB; off <<= 1) {
    int t = 0;
    if (tid >= off) t = s[tid - off];
    __syncthreads();
    if (tid >= off) s[tid] += t;
    __syncthreads();
  }
  int run = s[tid] - tot;
  if (idx4 < ND4) {
    int o[16];
#pragma unroll
    for (int q = 0; q < 16; ++q) { o[q] = run; run += c[q]; }
    int4* po = (int4*)(pb + (size_t)idx4 * 16);
    po[0] = make_int4(o[0], o[1], o[2], o[3]);
    po[1] = make_int4(o[4], o[5], o[6], o[7]);
    po[2] = make_int4(o[8], o[9], o[10], o[11]);
    po[3] = make_int4(o[12], o[13], o[14], o[15]);
  }
  if (tid == TPB - 1) bsum[blockIdx.x] = s[tid];
}

// ---------------- scan level 2: in-place exclusive scan of 977 block sums ----------
__global__ __launch_bounds__(1024) void scan2_kernel(int* __restrict__ b) {
  __shared__ int s[1024];
  int tid = threadIdx.x;
  int v = (tid < S1B) ? b[tid] : 0;
  s[tid] = v;
  __syncthreads();
  for (int off = 1; off < 1024; off <<= 1) {
    int t = 0;
    if (tid >= off) t = s[tid - off];
    __syncthreads();
    if (tid >= off) s[tid] += t;
    __syncthreads();
  }
  b[tid] = s[tid] - v;  // each thread only rewrites the slot it read; race-free
}

// ---------------- scatter into (dst,relation)-sorted keys ----------------
// u8 count-up cursor: returned dword field = slot (each field <=255, carry-free)
__global__ __launch_bounds__(TPB) void scatter_kernel(
    const int* __restrict__ src, const int* __restrict__ dst,
    const int* __restrict__ etype, const int* __restrict__ pb,
    const int* __restrict__ bofs, unsigned* __restrict__ cur,
    unsigned* __restrict__ keys) {
  int e = blockIdx.x * TPB + threadIdx.x;
  if (e >= NE) return;
  int r = etype[e];
  int p = dst[e] * NR + r;
  unsigned sh = (p & 3) * 8;
  unsigned old = atomicAdd(&cur[p >> 2], 1u << sh);
  int slot = (old >> sh) & 0xFF;
  keys[pb[p] + bofs[p >> 12] + slot] = (unsigned)src[e] | ((unsigned)r << 18);
}

// ---------------- layer-1 gather (R6-proven body; fp32 W in LDS) ----------------
__global__ __launch_bounds__(512, 8) void gather1_kernel(
    const float* __restrict__ x, const unsigned short* __restrict__ xb,
    const unsigned* __restrict__ keys, const int* __restrict__ pb,
    const int* __restrict__ bofs,
    const float* __restrict__ W1, const float* __restrict__ root1,
    const float* __restrict__ b1, unsigned short* __restrict__ h1) {
  __shared__ float Ws[NR * W1_RS];   // 25.9 KB
  __shared__ float Rs[H1D * W1_JS];
  __shared__ float Bs[H1D];
  for (int idx = threadIdx.x; idx < NR * 256; idx += 512) {
    int r = idx >> 8, rem = idx & 255, i = rem >> 4, j = rem & 15;
    Ws[r * W1_RS + j * W1_JS + i] = W1[idx];
  }
  for (int idx = threadIdx.x; idx < 256; idx += 512) {
    int i = idx >> 4, j = idx & 15;
    Rs[j * W1_JS + i] = root1[idx];
  }
  if (threadIdx.x < H1D) Bs[threadIdx.x] = b1[threadIdx.x];
  __syncthreads();

  int n = blockIdx.x * 32 + (threadIdx.x >> 4);   // 6250*32 == NN exact
  int j = threadIdx.x & 15;
  int p0 = n * NR;
  int start = pb[p0] + bofs[p0 >> 12];
  int end;
  if (n == NN - 1) end = NE;
  else { int p1 = p0 + NR; end = pb[p1] + bofs[p1 >> 12]; }

  float agg = 0.f, msum = 0.f, cntf = 0.f;
  unsigned key = 0;
  uint4 ra = {0, 0, 0, 0}, rb = {0, 0, 0, 0};
  if (start < end) {
    key = keys[start];
    const uint4* rp = (const uint4*)(xb + (size_t)(key & 0x3FFFFu) * FIN);
    ra = rp[0]; rb = rp[1];
  }
  for (int k = start; k < end; ++k) {
    unsigned r = key >> 18;
    uint4 ca = ra, cb = rb;
    unsigned nkey = 0xFFFFFFFFu;                  // sentinel forces final boundary
    if (k + 1 < end) {
      nkey = keys[k + 1];
      const uint4* rp = (const uint4*)(xb + (size_t)(nkey & 0x3FFFFu) * FIN);
      ra = rp[0]; rb = rp[1];
    }
    const float4* Wr = (const float4*)&Ws[r * W1_RS + j * W1_JS];
    float4 w0 = Wr[0], w1 = Wr[1], w2 = Wr[2], w3 = Wr[3];
    float m = 0.f;
    m = fmaf(bflo(ca.x), w0.x, m); m = fmaf(bfhi(ca.x), w0.y, m);
    m = fmaf(bflo(ca.y), w0.z, m); m = fmaf(bfhi(ca.y), w0.w, m);
    m = fmaf(bflo(ca.z), w1.x, m); m = fmaf(bfhi(ca.z), w1.y, m);
    m = fmaf(bflo(ca.w), w1.z, m); m = fmaf(bfhi(ca.w), w1.w, m);
    m = fmaf(bflo(cb.x), w2.x, m); m = fmaf(bfhi(cb.x), w2.y, m);
    m = fmaf(bflo(cb.y), w2.z, m); m = fmaf(bfhi(cb.y), w2.w, m);
    m = fmaf(bflo(cb.z), w3.x, m); m = fmaf(bfhi(cb.z), w3.y, m);
    m = fmaf(bflo(cb.w), w3.z, m); m = fmaf(bfhi(cb.w), w3.w, m);
    msum += m; cntf += 1.f;
    if ((nkey >> 18) != r) {                      // relation-run boundary -> mean
      agg = fmaf(msum, 1.0f / cntf, agg);
      msum = 0.f; cntf = 0.f;
    }
    key = nkey;
  }

  // root transform (fp32 x) + bias + relu -> bf16 h1
  const float4* xr = (const float4*)(x + (size_t)n * FIN);
  float4 x0 = xr[0], x1 = xr[1], x2 = xr[2], x3 = xr[3];
  const float4* Rr = (const float4*)&Rs[j * W1_JS];
  float4 r0 = Rr[0], r1 = Rr[1], r2 = Rr[2], r3 = Rr[3];
  float acc = Bs[j] + agg;
  acc = fmaf(x0.x, r0.x, acc); acc = fmaf(x0.y, r0.y, acc);
  acc = fmaf(x0.z, r0.z, acc); acc = fmaf(x0.w, r0.w, acc);
  acc = fmaf(x1.x, r1.x, acc); acc = fmaf(x1.y, r1.y, acc);
  acc = fmaf(x1.z, r1.z, acc); acc = fmaf(x1.w, r1.w, acc);
  acc = fmaf(x2.x, r2.x, acc); acc = fmaf(x2.y, r2.y, acc);
  acc = fmaf(x2.z, r2.z, acc); acc = fmaf(x2.w, r2.w, acc);
  acc = fmaf(x3.x, r3.x, acc); acc = fmaf(x3.y, r3.y, acc);
  acc = fmaf(x3.z, r3.z, acc); acc = fmaf(x3.w, r3.w, acc);
  h1[(size_t)n * H1D + j] = f2bf(fmaxf(acc, 0.f));
}

// ---------------- layer-2 gather (R6-proven body; packed bf16-pair W in LDS) ------
__global__ __launch_bounds__(512, 8) void gather2_kernel(
    const unsigned short* __restrict__ h1, const unsigned* __restrict__ keys,
    const int* __restrict__ pb, const int* __restrict__ bofs,
    const float* __restrict__ W2, const float* __restrict__ root2,
    const float* __restrict__ b2, unsigned short* __restrict__ h2) {
  __shared__ unsigned Wsu[NR * W2_RS];  // 26.2 KB: dword(i) = {W[i][j], W[i][j+16]}
  __shared__ float Rs[H1D * R2_JS];
  __shared__ float Bs[H2D];
  for (int idx = threadIdx.x; idx < NR * 256; idx += 512) {
    int r = idx >> 8, rem = idx & 255, j = rem >> 4, i = rem & 15;
    float lo = W2[r * 512 + i * 32 + j];
    float hi = W2[r * 512 + i * 32 + j + 16];
    Wsu[r * W2_RS + j * W2_JS + i] = (unsigned)f2bf(lo) | ((unsigned)f2bf(hi) << 16);
  }
  for (int idx = threadIdx.x; idx < 512; idx += 512) {
    int i = idx >> 5, jj = idx & 31;
    Rs[(jj & 15) * R2_JS + i * 2 + (jj >> 4)] = root2[idx];
  }
  if (threadIdx.x < H2D) Bs[threadIdx.x] = b2[threadIdx.x];
  __syncthreads();

  int n = blockIdx.x * 32 + (threadIdx.x >> 4);
  int j = threadIdx.x & 15;
  int p0 = n * NR;
  int start = pb[p0] + bofs[p0 >> 12];
  int end;
  if (n == NN - 1) end = NE;
  else { int p1 = p0 + NR; end = pb[p1] + bofs[p1 >> 12]; }

  float agg0 = 0.f, agg1 = 0.f, msum0 = 0.f, msum1 = 0.f, cntf = 0.f;
  unsigned key = 0;
  uint4 ra = {0, 0, 0, 0}, rb = {0, 0, 0, 0};
  if (start < end) {
    key = keys[start];
    const uint4* rp = (const uint4*)(h1 + (size_t)(key & 0x3FFFFu) * H1D);
    ra = rp[0]; rb = rp[1];
  }
  for (int k = start; k < end; ++k) {
    unsigned r = key >> 18;
    uint4 ca = ra, cb = rb;
    unsigned nkey = 0xFFFFFFFFu;
    if (k + 1 < end) {
      nkey = keys[k + 1];
      const uint4* rp = (const uint4*)(h1 + (size_t)(nkey & 0x3FFFFu) * H1D);
      ra = rp[0]; rb = rp[1];
    }
    const uint4* Wq = (const uint4*)&Wsu[r * W2_RS + j * W2_JS];
    uint4 q0 = Wq[0], q1 = Wq[1], q2 = Wq[2], q3 = Wq[3];
    float m0 = 0.f, m1 = 0.f;
#define G2STEP(xd, sel, wd) { float xi_ = sel(xd); \
    m0 = fmaf(xi_, bflo(wd), m0); m1 = fmaf(xi_, bfhi(wd), m1); }
    G2STEP(ca.x, bflo, q0.x) G2STEP(ca.x, bfhi, q0.y)
    G2STEP(ca.y, bflo, q0.z) G2STEP(ca.y, bfhi, q0.w)
    G2STEP(ca.z, bflo, q1.x) G2STEP(ca.z, bfhi, q1.y)
    G2STEP(ca.w, bflo, q1.z) G2STEP(ca.w, bfhi, q1.w)
    G2STEP(cb.x, bflo, q2.x) G2STEP(cb.x, bfhi, q2.y)
    G2STEP(cb.y, bflo, q2.z) G2STEP(cb.y, bfhi, q2.w)
    G2STEP(cb.z, bflo, q3.x) G2STEP(cb.z, bfhi, q3.y)
    G2STEP(cb.w, bflo, q3.z) G2STEP(cb.w, bfhi, q3.w)
#undef G2STEP
    msum0 += m0; msum1 += m1; cntf += 1.f;
    if ((nkey >> 18) != r) {
      float nv = 1.0f / cntf;
      agg0 = fmaf(msum0, nv, agg0);
      agg1 = fmaf(msum1, nv, agg1);
      msum0 = 0.f; msum1 = 0.f; cntf = 0.f;
    }
    key = nkey;
  }

  // root transform (bf16 h1 row) + bias + relu -> bf16 h2
  const uint4* hr = (const uint4*)(h1 + (size_t)n * H1D);
  uint4 ha = hr[0], hb = hr[1];
  const float4* Rr = (const float4*)&Rs[j * R2_JS];
  float c0 = Bs[j] + agg0, c1 = Bs[j + 16] + agg1;
  float4 w;
  w = Rr[0]; c0 = fmaf(bflo(ha.x), w.x, c0); c1 = fmaf(bflo(ha.x), w.y, c1);
             c0 = fmaf(bfhi(ha.x), w.z, c0); c1 = fmaf(bfhi(ha.x), w.w, c1);
  w = Rr[1]; c0 = fmaf(bflo(ha.y), w.x, c0); c1 = fmaf(bflo(ha.y), w.y, c1);
             c0 = fmaf(bfhi(ha.y), w.z, c0); c1 = fmaf(bfhi(ha.y), w.w, c1);
  w = Rr[2]; c0 = fmaf(bflo(ha.z), w.x, c0); c1 = fmaf(bflo(ha.z), w.y, c1);
             c0 = fmaf(bfhi(ha.z), w.z, c0); c1 = fmaf(bfhi(ha.z), w.w, c1);
  w = Rr[3]; c0 = fmaf(bflo(ha.w), w.x, c0); c1 = fmaf(bflo(ha.w), w.y, c1);
             c0 = fmaf(bfhi(ha.w), w.z, c0); c1 = fmaf(bfhi(ha.w), w.w, c1);
  w = Rr[4]; c0 = fmaf(bflo(hb.x), w.x, c0); c1 = fmaf(bflo(hb.x), w.y, c1);
             c0 = fmaf(bfhi(hb.x), w.z, c0); c1 = fmaf(bfhi(hb.x), w.w, c1);
  w = Rr[5]; c0 = fmaf(bflo(hb.y), w.x, c0); c1 = fmaf(bflo(hb.y), w.y, c1);
             c0 = fmaf(bfhi(hb.y), w.z, c0); c1 = fmaf(bfhi(hb.y), w.w, c1);
  w = Rr[6]; c0 = fmaf(bflo(hb.z), w.x, c0); c1 = fmaf(bflo(hb.z), w.y, c1);
             c0 = fmaf(bfhi(hb.z), w.z, c0); c1 = fmaf(bfhi(hb.z), w.w, c1);
  w = Rr[7]; c0 = fmaf(bflo(hb.w), w.x, c0); c1 = fmaf(bflo(hb.w), w.y, c1);
             c0 = fmaf(bfhi(hb.w), w.z, c0); c1 = fmaf(bfhi(hb.w), w.w, c1);
  h2[(size_t)n * H2D + j]      = f2bf(fmaxf(c0, 0.f));
  h2[(size_t)n * H2D + 16 + j] = f2bf(fmaxf(c1, 0.f));
}

// ---------------- graph mean-pool partials ----------------
__global__ __launch_bounds__(TPB) void pool_kernel(
    const unsigned short* __restrict__ h2, const int* __restrict__ batch,
    float* __restrict__ gsum, float* __restrict__ gcnt) {
  __shared__ float Gs[8 * H2D];
  __shared__ float Gc[8];
  __shared__ int Bb[TPB];
  int tid = threadIdx.x;
  int base = blockIdx.x * TPB;
  if (tid < 8) Gc[tid] = 0.f;
  if (tid < 8 * H2D) Gs[tid] = 0.f;
  int n = base + tid;
  int g = (n < NN) ? batch[n] : -1;
  Bb[tid] = g;
  __syncthreads();
  int gmin = Bb[0];  // batch sorted ascending
  if (n < NN) {
    int gg = g - gmin;
    if (gg < 8) atomicAdd(&Gc[gg], 1.f);
    else atomicAdd(&gcnt[g], 1.f);
  }
  for (int i = tid; i < TPB * H2D; i += TPB) {
    int nl = i >> 5, j = i & 31;
    int nn = base + nl;
    if (nn < NN) {
      int gg = Bb[nl] - gmin;
      float v = __uint_as_float(((unsigned)h2[(size_t)nn * H2D + j]) << 16);
      if (gg < 8) atomicAdd(&Gs[gg * H2D + j], v);
      else atomicAdd(&gsum[Bb[nl] * H2D + j], v);
    }
  }
  __syncthreads();
  if (tid < 8 * H2D) {
    float v = Gs[tid];
    int g2 = gmin + (tid >> 5);
    if (v != 0.f && g2 < NG) atomicAdd(&gsum[g2 * H2D + (tid & 31)], v);
  }
  if (tid < 8) {
    float v = Gc[tid];
    if (v != 0.f && gmin + tid < NG) atomicAdd(&gcnt[gmin + tid], v);
  }
}

// ---------------- final head ----------------
__global__ __launch_bounds__(128) void final_kernel(
    const float* __restrict__ gsum, const float* __restrict__ gcnt,
    const float* __restrict__ fcW, const float* __restrict__ fcb,
    float* __restrict__ out) {
  int t = threadIdx.x;
  if (t >= NG * NC) return;
  int g = t >> 1, c = t & 1;
  float cnt = fmaxf(gcnt[g], 1.0f);
  float acc = fcb[c];
#pragma unroll
  for (int jj = 0; jj < H2D; ++jj)
    acc = fmaf(gsum[g * H2D + jj] / cnt, fcW[jj * NC + c], acc);
  out[t] = acc;
}

}  // namespace

extern "C" void kernel_launch(void* const* d_in, const int* in_sizes, int n_in,
                              void* d_out, int out_size, void* d_ws, size_t ws_size,
                              hipStream_t stream) {
  (void)in_sizes; (void)n_in; (void)out_size; (void)ws_size;

  const float* x     = (const float*)d_in[0];
  const int*   ei    = (const int*)d_in[1];
  const int*   etype = (const int*)d_in[2];
  const int*   batch = (const int*)d_in[3];
  const float* W1    = (const float*)d_in[4];
  const float* root1 = (const float*)d_in[5];
  const float* b1    = (const float*)d_in[6];
  const float* W2    = (const float*)d_in[7];
  const float* root2 = (const float*)d_in[8];
  const float* b2    = (const float*)d_in[9];
  const float* fcW   = (const float*)d_in[10];
  const float* fcb   = (const float*)d_in[11];

  const int* src = ei;
  const int* dst = ei + NE;

  // workspace layout (bytes, 256-aligned offsets)
  char* ws = (char*)d_ws;
  unsigned*       cnt   = (unsigned*)(ws + 0);           //  4,000,000 (u8 x 4M)
  unsigned*       cur   = (unsigned*)(ws + 4000000);     //  4,000,000 (u8 x 4M)
  int*            pb    = (int*)(ws + 8000000);          // 16,000,000
  int*            bofs  = (int*)(ws + 24000000);         //      4,096 (1024 ints)
  unsigned*       keys  = (unsigned*)(ws + 24004096);    // 12,800,000
  unsigned short* xb    = (unsigned short*)(ws + 36804096); // 6,400,000
  unsigned short* h1    = (unsigned short*)(ws + 43204096); // 6,400,000
  unsigned short* h2    = (unsigned short*)(ws + 49604096); // 12,800,000
  float*          gsum  = (float*)(ws + 62404096);       //      8,192
  float*          gcnt  = (float*)(ws + 62412288);       //        256
  // total: 62,412,544 B

  hipMemsetAsync(ws, 0, 8000000, stream);            // cnt + cur
  hipMemsetAsync(ws + 62404096, 0, 8448, stream);    // gsum + gcnt

  int egrid = (NE + TPB - 1) / TPB;   // 12500
  int ggrid = NN / 32;                // 6250

  xprep_kernel<<<3125, TPB, 0, stream>>>(x, xb);
  count_kernel<<<egrid, TPB, 0, stream>>>(etype, dst, cnt);
  scan1_kernel<<<S1B, TPB, 0, stream>>>((const uint4*)cnt, pb, bofs);
  scan2_kernel<<<1, 1024, 0, stream>>>(bofs);
  scatter_kernel<<<egrid, TPB, 0, stream>>>(src, dst, etype, pb, bofs, cur, keys);
  gather1_kernel<<<ggrid, 512, 0, stream>>>(x, xb, keys, pb, bofs, W1, root1, b1, h1);
  gather2_kernel<<<ggrid, 512, 0, stream>>>(h1, keys, pb, bofs, W2, root2, b2, h2);
  pool_kernel<<<NB, TPB, 0, stream>>>(h2, batch, gsum, gcnt);
  final_kernel<<<1, 128, 0, stream>>>(gsum, gcnt, fcW, fcb, (float*)d_out);
}

// Round 11
// 684.172 us; speedup vs baseline: 11.7897x; 1.1880x over previous
//
#include <hip/hip_runtime.h>

namespace {

constexpr int NN  = 200000;   // nodes
constexpr int NE  = 3200000;  // edges
constexpr int NR  = 20;       // relations
constexpr int FIN = 16;
constexpr int H1D = 16;
constexpr int H2D = 32;
constexpr int NC  = 2;
constexpr int NG  = 64;
constexpr int NP  = NN * NR;  // 4,000,000 pairs (p = d*NR + r)
constexpr int ND4 = NP / 16;  // 250,000 uint4's of packed u8 counts

constexpr int TPB = 256;
constexpr int NB  = (NN + TPB - 1) / TPB;   // 782
constexpr int S1B = (ND4 + TPB - 1) / TPB;  // 977 scan level-1 blocks (4096 pairs each)

// gather1 W1 LDS: bf16 reduction-pairs per (r,j): 8 dwords, dword k = {W[2k][j], W[2k+1][j]}.
// j-stride 12 dwords (48B, 16B-aligned), r-stride 196 dwords. 15.7 KB.
constexpr int JS1 = 12, RS1 = 196;
// gather2 W2 LDS: per (r,j) 16 dwords: kk<8 -> channel j pairs {W[2k][j],W[2k+1][j]},
// kk>=8 -> channel j+16 pairs. j-stride 20 dwords, r-stride 328 dwords. 26.2 KB.
constexpr int JS2 = 20, RS2 = 328;
constexpr int R2_JS = 36;                   // gather2 root fp32 pair stride

__device__ __forceinline__ float bflo(unsigned d) { return __uint_as_float(d << 16); }
__device__ __forceinline__ float bfhi(unsigned d) { return __uint_as_float(d & 0xFFFF0000u); }
__device__ __forceinline__ unsigned short f2bf(float f) {  // round-to-nearest-even
  unsigned u = __float_as_uint(f);
  return (unsigned short)((u + 0x7FFFu + ((u >> 16) & 1u)) >> 16);
}

// 2x bf16 MAC with fp32 accumulate via the COMPILER BUILTIN (correct VOP3P encoding;
// R8's hand-asm version produced wrong results — op_sel_hi default suspected).
typedef __bf16 bf2 __attribute__((ext_vector_type(2)));
__device__ __forceinline__ float dot2bf(unsigned a, unsigned b, float c) {
  return __builtin_amdgcn_fdot2_f32_bf16(__builtin_bit_cast(bf2, a),
                                         __builtin_bit_cast(bf2, b), c, false);
}

// ---------------- x -> bf16 prep ----------------
__global__ __launch_bounds__(TPB) void xprep_kernel(
    const float* __restrict__ x, unsigned short* __restrict__ xb) {
  int t = blockIdx.x * TPB + threadIdx.x;
  if (t >= (NN * FIN) / 4) return;
  float4 v = ((const float4*)x)[t];
  ushort4 o;
  o.x = f2bf(v.x); o.y = f2bf(v.y); o.z = f2bf(v.z); o.w = f2bf(v.w);
  ((ushort4*)xb)[t] = o;
}

// ---------------- per-(dst,relation) counts, u8-packed; atomic return = edge slot ----
__global__ __launch_bounds__(TPB) void count_kernel(
    const int* __restrict__ etype, const int* __restrict__ dst,
    unsigned* __restrict__ cnt, unsigned char* __restrict__ slotv) {
  int e = blockIdx.x * TPB + threadIdx.x;
  if (e >= NE) return;
  int p = dst[e] * NR + etype[e];
  unsigned sh = (p & 3) * 8;
  unsigned old = atomicAdd(&cnt[p >> 2], 1u << sh);
  slotv[e] = (unsigned char)((old >> sh) & 0xFF);   // rank within pair
}

// ---------------- scan level 1: 4096 pairs/block -> pb (block-local excl) + bsum ----
__global__ __launch_bounds__(TPB) void scan1_kernel(
    const uint4* __restrict__ cnt4, int* __restrict__ pb, int* __restrict__ bsum) {
  __shared__ int s[TPB];
  int tid = threadIdx.x;
  int idx4 = blockIdx.x * TPB + tid;
  uint4 cd = make_uint4(0, 0, 0, 0);
  if (idx4 < ND4) cd = cnt4[idx4];
  unsigned dws[4] = {cd.x, cd.y, cd.z, cd.w};
  int c[16];
#pragma unroll
  for (int q = 0; q < 4; ++q) {
    c[q * 4 + 0] = dws[q] & 0xFF;
    c[q * 4 + 1] = (dws[q] >> 8) & 0xFF;
    c[q * 4 + 2] = (dws[q] >> 16) & 0xFF;
    c[q * 4 + 3] = dws[q] >> 24;
  }
  int tot = 0;
#pragma unroll
  for (int q = 0; q < 16; ++q) tot += c[q];
  s[tid] = tot;
  __syncthreads();
  for (int off = 1; off < TPB; off <<= 1) {
    int t = 0;
    if (tid >= off) t = s[tid - off];
    __syncthreads();
    if (tid >= off) s[tid] += t;
    __syncthreads();
  }
  int run = s[tid] - tot;
  if (idx4 < ND4) {
    int o[16];
#pragma unroll
    for (int q = 0; q < 16; ++q) { o[q] = run; run += c[q]; }
    int4* po = (int4*)(pb + (size_t)idx4 * 16);
    po[0] = make_int4(o[0], o[1], o[2], o[3]);
    po[1] = make_int4(o[4], o[5], o[6], o[7]);
    po[2] = make_int4(o[8], o[9], o[10], o[11]);
    po[3] = make_int4(o[12], o[13], o[14], o[15]);
  }
  if (tid == TPB - 1) bsum[blockIdx.x] = s[tid];
}

// ---------------- scan level 2: in-place exclusive scan of 977 block sums ----------
__global__ __launch_bounds__(1024) void scan2_kernel(int* __restrict__ b) {
  __shared__ int s[1024];
  int tid = threadIdx.x;
  int v = (tid < S1B) ? b[tid] : 0;
  s[tid] = v;
  __syncthreads();
  for (int off = 1; off < 1024; off <<= 1) {
    int t = 0;
    if (tid >= off) t = s[tid - off];
    __syncthreads();
    if (tid >= off) s[tid] += t;
    __syncthreads();
  }
  b[tid] = s[tid] - v;  // each thread only rewrites the slot it read; race-free
}

// ---------------- scatter into (dst,relation)-sorted keys (no atomics) ----------
__global__ __launch_bounds__(TPB) void scatter_kernel(
    const int* __restrict__ src, const int* __restrict__ dst,
    const int* __restrict__ etype, const int* __restrict__ pb,
    const int* __restrict__ bofs, const unsigned char* __restrict__ slotv,
    unsigned* __restrict__ keys) {
  int e = blockIdx.x * TPB + threadIdx.x;
  if (e >= NE) return;
  int r = etype[e];
  int p = dst[e] * NR + r;
  int slot = slotv[e];
  keys[pb[p] + bofs[p >> 12] + slot] = (unsigned)src[e] | ((unsigned)r << 18);
}

// ---------------- layer-1 gather: 16 lanes/node, lane = out channel, dot2 ----------
__global__ __launch_bounds__(512, 8) void gather1_kernel(
    const float* __restrict__ x, const unsigned short* __restrict__ xb,
    const unsigned* __restrict__ keys, const int* __restrict__ pb,
    const int* __restrict__ bofs,
    const float* __restrict__ W1, const float* __restrict__ root1,
    const float* __restrict__ b1, unsigned short* __restrict__ h1) {
  __shared__ unsigned Ws[NR * RS1];   // 15.7 KB bf16 reduction-pairs
  __shared__ float Rs[H1D * 20];      // root1 fp32, transposed
  __shared__ float Bs[H1D];
  for (int idx = threadIdx.x; idx < NR * 128; idx += 512) {
    int r = idx >> 7, rem = idx & 127, j = rem >> 3, k = rem & 7;
    float lo = W1[r * 256 + (2 * k) * 16 + j];
    float hi = W1[r * 256 + (2 * k + 1) * 16 + j];
    Ws[r * RS1 + j * JS1 + k] = (unsigned)f2bf(lo) | ((unsigned)f2bf(hi) << 16);
  }
  for (int idx = threadIdx.x; idx < 256; idx += 512) {
    int i = idx >> 4, j = idx & 15;
    Rs[j * 20 + i] = root1[idx];
  }
  if (threadIdx.x < H1D) Bs[threadIdx.x] = b1[threadIdx.x];
  __syncthreads();

  int n = blockIdx.x * 32 + (threadIdx.x >> 4);   // 6250*32 == NN exact
  int j = threadIdx.x & 15;
  int p0 = n * NR;
  int start = pb[p0] + bofs[p0 >> 12];
  int end;
  if (n == NN - 1) end = NE;
  else { int p1 = p0 + NR; end = pb[p1] + bofs[p1 >> 12]; }

  float agg = 0.f, msum = 0.f, cntf = 0.f;
  unsigned key = 0;
  uint4 ra = {0, 0, 0, 0}, rb = {0, 0, 0, 0};
  if (start < end) {
    key = keys[start];
    const uint4* rp = (const uint4*)(xb + (size_t)(key & 0x3FFFFu) * FIN);
    ra = rp[0]; rb = rp[1];
  }
  for (int k = start; k < end; ++k) {
    unsigned r = key >> 18;
    uint4 ca = ra, cb = rb;
    unsigned nkey = 0xFFFFFFFFu;                  // sentinel forces final boundary
    if (k + 1 < end) {
      nkey = keys[k + 1];
      const uint4* rp = (const uint4*)(xb + (size_t)(nkey & 0x3FFFFu) * FIN);
      ra = rp[0]; rb = rp[1];
    }
    const uint4* Wq = (const uint4*)&Ws[r * RS1 + j * JS1];
    uint4 q0 = Wq[0], q1 = Wq[1];
    float m = 0.f;
    m = dot2bf(ca.x, q0.x, m); m = dot2bf(ca.y, q0.y, m);
    m = dot2bf(ca.z, q0.z, m); m = dot2bf(ca.w, q0.w, m);
    m = dot2bf(cb.x, q1.x, m); m = dot2bf(cb.y, q1.y, m);
    m = dot2bf(cb.z, q1.z, m); m = dot2bf(cb.w, q1.w, m);
    msum += m; cntf += 1.f;
    if ((nkey >> 18) != r) {                      // relation-run boundary -> mean
      agg = fmaf(msum, 1.0f / cntf, agg);
      msum = 0.f; cntf = 0.f;
    }
    key = nkey;
  }

  // root transform (fp32 x, fp32 root) + bias + relu -> bf16 h1
  const float4* xr = (const float4*)(x + (size_t)n * FIN);
  float4 x0 = xr[0], x1 = xr[1], x2 = xr[2], x3 = xr[3];
  const float4* Rr = (const float4*)&Rs[j * 20];
  float4 r0 = Rr[0], r1 = Rr[1], r2 = Rr[2], r3 = Rr[3];
  float acc = Bs[j] + agg;
  acc = fmaf(x0.x, r0.x, acc); acc = fmaf(x0.y, r0.y, acc);
  acc = fmaf(x0.z, r0.z, acc); acc = fmaf(x0.w, r0.w, acc);
  acc = fmaf(x1.x, r1.x, acc); acc = fmaf(x1.y, r1.y, acc);
  acc = fmaf(x1.z, r1.z, acc); acc = fmaf(x1.w, r1.w, acc);
  acc = fmaf(x2.x, r2.x, acc); acc = fmaf(x2.y, r2.y, acc);
  acc = fmaf(x2.z, r2.z, acc); acc = fmaf(x2.w, r2.w, acc);
  acc = fmaf(x3.x, r3.x, acc); acc = fmaf(x3.y, r3.y, acc);
  acc = fmaf(x3.z, r3.z, acc); acc = fmaf(x3.w, r3.w, acc);
  h1[(size_t)n * H1D + j] = f2bf(fmaxf(acc, 0.f));
}

// ---------------- layer-2 gather: 16 lanes/node, lane = channels j & j+16, dot2 ----
__global__ __launch_bounds__(512, 8) void gather2_kernel(
    const unsigned short* __restrict__ h1, const unsigned* __restrict__ keys,
    const int* __restrict__ pb, const int* __restrict__ bofs,
    const float* __restrict__ W2, const float* __restrict__ root2,
    const float* __restrict__ b2, unsigned short* __restrict__ h2) {
  __shared__ unsigned Wsu[NR * RS2];  // 26.2 KB bf16 reduction-pairs, 2 channel halves
  __shared__ float Rs[H1D * R2_JS];
  __shared__ float Bs[H2D];
  for (int idx = threadIdx.x; idx < NR * 256; idx += 512) {
    int r = idx >> 8, rem = idx & 255;
    int j = rem >> 4, kk = rem & 15;
    int k = kk & 7, half = kk >> 3;
    int col = j + half * 16;
    float lo = W2[r * 512 + (2 * k) * 32 + col];
    float hi = W2[r * 512 + (2 * k + 1) * 32 + col];
    Wsu[r * RS2 + j * JS2 + kk] = (unsigned)f2bf(lo) | ((unsigned)f2bf(hi) << 16);
  }
  for (int idx = threadIdx.x; idx < 512; idx += 512) {
    int i = idx >> 5, jj = idx & 31;
    Rs[(jj & 15) * R2_JS + i * 2 + (jj >> 4)] = root2[idx];
  }
  if (threadIdx.x < H2D) Bs[threadIdx.x] = b2[threadIdx.x];
  __syncthreads();

  int n = blockIdx.x * 32 + (threadIdx.x >> 4);
  int j = threadIdx.x & 15;
  int p0 = n * NR;
  int start = pb[p0] + bofs[p0 >> 12];
  int end;
  if (n == NN - 1) end = NE;
  else { int p1 = p0 + NR; end = pb[p1] + bofs[p1 >> 12]; }

  float agg0 = 0.f, agg1 = 0.f, msum0 = 0.f, msum1 = 0.f, cntf = 0.f;
  unsigned key = 0;
  uint4 ra = {0, 0, 0, 0}, rb = {0, 0, 0, 0};
  if (start < end) {
    key = keys[start];
    const uint4* rp = (const uint4*)(h1 + (size_t)(key & 0x3FFFFu) * H1D);
    ra = rp[0]; rb = rp[1];
  }
  for (int k = start; k < end; ++k) {
    unsigned r = key >> 18;
    uint4 ca = ra, cb = rb;
    unsigned nkey = 0xFFFFFFFFu;
    if (k + 1 < end) {
      nkey = keys[k + 1];
      const uint4* rp = (const uint4*)(h1 + (size_t)(nkey & 0x3FFFFu) * H1D);
      ra = rp[0]; rb = rp[1];
    }
    const uint4* Wq = (const uint4*)&Wsu[r * RS2 + j * JS2];
    uint4 q0 = Wq[0], q1 = Wq[1], q2 = Wq[2], q3 = Wq[3];
    float m0 = 0.f, m1 = 0.f;
    m0 = dot2bf(ca.x, q0.x, m0); m0 = dot2bf(ca.y, q0.y, m0);
    m0 = dot2bf(ca.z, q0.z, m0); m0 = dot2bf(ca.w, q0.w, m0);
    m0 = dot2bf(cb.x, q1.x, m0); m0 = dot2bf(cb.y, q1.y, m0);
    m0 = dot2bf(cb.z, q1.z, m0); m0 = dot2bf(cb.w, q1.w, m0);
    m1 = dot2bf(ca.x, q2.x, m1); m1 = dot2bf(ca.y, q2.y, m1);
    m1 = dot2bf(ca.z, q2.z, m1); m1 = dot2bf(ca.w, q2.w, m1);
    m1 = dot2bf(cb.x, q3.x, m1); m1 = dot2bf(cb.y, q3.y, m1);
    m1 = dot2bf(cb.z, q3.z, m1); m1 = dot2bf(cb.w, q3.w, m1);
    msum0 += m0; msum1 += m1; cntf += 1.f;
    if ((nkey >> 18) != r) {
      float nv = 1.0f / cntf;
      agg0 = fmaf(msum0, nv, agg0);
      agg1 = fmaf(msum1, nv, agg1);
      msum0 = 0.f; msum1 = 0.f; cntf = 0.f;
    }
    key = nkey;
  }

  // root transform (bf16 h1 row, fp32 root) + bias + relu -> bf16 h2
  const uint4* hr = (const uint4*)(h1 + (size_t)n * H1D);
  uint4 ha = hr[0], hb = hr[1];
  const float4* Rr = (const float4*)&Rs[j * R2_JS];
  float c0 = Bs[j] + agg0, c1 = Bs[j + 16] + agg1;
  float4 w;
  w = Rr[0]; c0 = fmaf(bflo(ha.x), w.x, c0); c1 = fmaf(bflo(ha.x), w.y, c1);
             c0 = fmaf(bfhi(ha.x), w.z, c0); c1 = fmaf(bfhi(ha.x), w.w, c1);
  w = Rr[1]; c0 = fmaf(bflo(ha.y), w.x, c0); c1 = fmaf(bflo(ha.y), w.y, c1);
             c0 = fmaf(bfhi(ha.y), w.z, c0); c1 = fmaf(bfhi(ha.y), w.w, c1);
  w = Rr[2]; c0 = fmaf(bflo(ha.z), w.x, c0); c1 = fmaf(bflo(ha.z), w.y, c1);
             c0 = fmaf(bfhi(ha.z), w.z, c0); c1 = fmaf(bfhi(ha.z), w.w, c1);
  w = Rr[3]; c0 = fmaf(bflo(ha.w), w.x, c0); c1 = fmaf(bflo(ha.w), w.y, c1);
             c0 = fmaf(bfhi(ha.w), w.z, c0); c1 = fmaf(bfhi(ha.w), w.w, c1);
  w = Rr[4]; c0 = fmaf(bflo(hb.x), w.x, c0); c1 = fmaf(bflo(hb.x), w.y, c1);
             c0 = fmaf(bfhi(hb.x), w.z, c0); c1 = fmaf(bfhi(hb.x), w.w, c1);
  w = Rr[5]; c0 = fmaf(bflo(hb.y), w.x, c0); c1 = fmaf(bflo(hb.y), w.y, c1);
             c0 = fmaf(bfhi(hb.y), w.z, c0); c1 = fmaf(bfhi(hb.y), w.w, c1);
  w = Rr[6]; c0 = fmaf(bflo(hb.z), w.x, c0); c1 = fmaf(bflo(hb.z), w.y, c1);
             c0 = fmaf(bfhi(hb.z), w.z, c0); c1 = fmaf(bfhi(hb.z), w.w, c1);
  w = Rr[7]; c0 = fmaf(bflo(hb.w), w.x, c0); c1 = fmaf(bflo(hb.w), w.y, c1);
             c0 = fmaf(bfhi(hb.w), w.z, c0); c1 = fmaf(bfhi(hb.w), w.w, c1);
  h2[(size_t)n * H2D + j]      = f2bf(fmaxf(c0, 0.f));
  h2[(size_t)n * H2D + 16 + j] = f2bf(fmaxf(c1, 0.f));
}

// ---------------- graph mean-pool partials ----------------
__global__ __launch_bounds__(TPB) void pool_kernel(
    const unsigned short* __restrict__ h2, const int* __restrict__ batch,
    float* __restrict__ gsum, float* __restrict__ gcnt) {
  __shared__ float Gs[8 * H2D];
  __shared__ float Gc[8];
  __shared__ int Bb[TPB];
  int tid = threadIdx.x;
  int base = blockIdx.x * TPB;
  if (tid < 8) Gc[tid] = 0.f;
  if (tid < 8 * H2D) Gs[tid] = 0.f;
  int n = base + tid;
  int g = (n < NN) ? batch[n] : -1;
  Bb[tid] = g;
  __syncthreads();
  int gmin = Bb[0];  // batch sorted ascending
  if (n < NN) {
    int gg = g - gmin;
    if (gg < 8) atomicAdd(&Gc[gg], 1.f);
    else atomicAdd(&gcnt[g], 1.f);
  }
  for (int i = tid; i < TPB * H2D; i += TPB) {
    int nl = i >> 5, j = i & 31;
    int nn = base + nl;
    if (nn < NN) {
      int gg = Bb[nl] - gmin;
      float v = __uint_as_float(((unsigned)h2[(size_t)nn * H2D + j]) << 16);
      if (gg < 8) atomicAdd(&Gs[gg * H2D + j], v);
      else atomicAdd(&gsum[Bb[nl] * H2D + j], v);
    }
  }
  __syncthreads();
  if (tid < 8 * H2D) {
    float v = Gs[tid];
    int g2 = gmin + (tid >> 5);
    if (v != 0.f && g2 < NG) atomicAdd(&gsum[g2 * H2D + (tid & 31)], v);
  }
  if (tid < 8) {
    float v = Gc[tid];
    if (v != 0.f && gmin + tid < NG) atomicAdd(&gcnt[gmin + tid], v);
  }
}

// ---------------- final head ----------------
__global__ __launch_bounds__(128) void final_kernel(
    const float* __restrict__ gsum, const float* __restrict__ gcnt,
    const float* __restrict__ fcW, const float* __restrict__ fcb,
    float* __restrict__ out) {
  int t = threadIdx.x;
  if (t >= NG * NC) return;
  int g = t >> 1, c = t & 1;
  float cnt = fmaxf(gcnt[g], 1.0f);
  float acc = fcb[c];
#pragma unroll
  for (int jj = 0; jj < H2D; ++jj)
    acc = fmaf(gsum[g * H2D + jj] / cnt, fcW[jj * NC + c], acc);
  out[t] = acc;
}

}  // namespace

extern "C" void kernel_launch(void* const* d_in, const int* in_sizes, int n_in,
                              void* d_out, int out_size, void* d_ws, size_t ws_size,
                              hipStream_t stream) {
  (void)in_sizes; (void)n_in; (void)out_size; (void)ws_size;

  const float* x     = (const float*)d_in[0];
  const int*   ei    = (const int*)d_in[1];
  const int*   etype = (const int*)d_in[2];
  const int*   batch = (const int*)d_in[3];
  const float* W1    = (const float*)d_in[4];
  const float* root1 = (const float*)d_in[5];
  const float* b1    = (const float*)d_in[6];
  const float* W2    = (const float*)d_in[7];
  const float* root2 = (const float*)d_in[8];
  const float* b2    = (const float*)d_in[9];
  const float* fcW   = (const float*)d_in[10];
  const float* fcb   = (const float*)d_in[11];

  const int* src = ei;
  const int* dst = ei + NE;

  // workspace layout (bytes, 16B-aligned offsets)
  char* ws = (char*)d_ws;
  unsigned*       cnt   = (unsigned*)(ws + 0);               //  4,000,000 (u8 x 4M)
  unsigned char*  slotv = (unsigned char*)(ws + 4000000);    //  3,200,000
  int*            pb    = (int*)(ws + 7200000);              // 16,000,000
  int*            bofs  = (int*)(ws + 23200000);             //      4,096
  unsigned*       keys  = (unsigned*)(ws + 23204096);        // 12,800,000
  unsigned short* xb    = (unsigned short*)(ws + 36004096);  //  6,400,000
  unsigned short* h1    = (unsigned short*)(ws + 42404096);  //  6,400,000
  unsigned short* h2    = (unsigned short*)(ws + 48804096);  // 12,800,000
  float*          gsum  = (float*)(ws + 61604096);           //      8,192
  float*          gcnt  = (float*)(ws + 61612288);           //        256
  // total: 61,612,544 B

  hipMemsetAsync(ws, 0, 4000000, stream);            // cnt only (slotv fully written)
  hipMemsetAsync(ws + 61604096, 0, 8448, stream);    // gsum + gcnt

  int egrid = (NE + TPB - 1) / TPB;   // 12500
  int ggrid = NN / 32;                // 6250

  xprep_kernel<<<3125, TPB, 0, stream>>>(x, xb);
  count_kernel<<<egrid, TPB, 0, stream>>>(etype, dst, cnt, slotv);
  scan1_kernel<<<S1B, TPB, 0, stream>>>((const uint4*)cnt, pb, bofs);
  scan2_kernel<<<1, 1024, 0, stream>>>(bofs);
  scatter_kernel<<<egrid, TPB, 0, stream>>>(src, dst, etype, pb, bofs, slotv, keys);
  gather1_kernel<<<ggrid, 512, 0, stream>>>(x, xb, keys, pb, bofs, W1, root1, b1, h1);
  gather2_kernel<<<ggrid, 512, 0, stream>>>(h1, keys, pb, bofs, W2, root2, b2, h2);
  pool_kernel<<<NB, TPB, 0, stream>>>(h2, batch, gsum, gcnt);
  final_kernel<<<1, 128, 0, stream>>>(gsum, gcnt, fcW, fcb, (float*)d_out);
}